// Round 1
// 408.227 us; speedup vs baseline: 1.0959x; 1.0959x over previous
//
#include <hip/hip_runtime.h>
#include <hip/hip_bf16.h>
#include <math.h>

// Problem constants
constexpr int kB = 4;
constexpr int kN = 2048;
constexpr int kC = 256;
constexpr int kDFF = 1024;
constexpr int kKNN = 16;
constexpr int kDH = 64;

typedef __attribute__((ext_vector_type(8))) short short8;
typedef __attribute__((ext_vector_type(4))) float float4v;

__device__ __forceinline__ float gelu_erf(float x) {
    return 0.5f * x * (1.0f + erff(x * 0.70710678118654752440f));
}

// fp32 -> bf16 bits, round-to-nearest-even (bit-exact with HW conversion)
__device__ __forceinline__ short f2b(float f) {
    unsigned u = __float_as_uint(f);
    u = u + 0x7FFFu + ((u >> 16) & 1u);
    return (short)(u >> 16);
}

// ---------------------------------------------------------------------------
// 1) input_proj tiled fp32 (src is K-major; only 2 GF -- stays on vector ALU)
// ---------------------------------------------------------------------------
__global__ __launch_bounds__(256) void proj_gemm(
    const float* __restrict__ src1, const float* __restrict__ src2,
    const float* __restrict__ Wp, const float* __restrict__ bp,
    float* __restrict__ x1, float* __restrict__ x2)
{
    constexpr int BM = 64, BN = 64, BK = 16;
    __shared__ float As[BK][BM + 1];
    __shared__ float Bs[BK][BN + 1];

    const int z = blockIdx.z;
    const int b = z & 3;
    const float* A = (z < 4 ? src1 : src2) + (size_t)b * kC * kN;  // (C x N)
    float* out = (z < 4 ? x1 : x2) + (size_t)b * kN * kC;

    const int tid = threadIdx.x;
    const int n0 = blockIdx.x * BN;
    const int m0 = blockIdx.y * BM;
    const int tx = tid & 15, ty = tid >> 4;

    float acc[4][4] = {};
    for (int k0 = 0; k0 < kC; k0 += BK) {
        #pragma unroll
        for (int q = 0; q < 4; q++) {
            int e = tid + q * 256;
            int kk = e >> 6, mm = e & 63;
            As[kk][mm] = A[(size_t)(k0 + kk) * kN + (m0 + mm)];
        }
        #pragma unroll
        for (int q = 0; q < 4; q++) {
            int e = tid + q * 256;
            int nn = e >> 4, kk = e & 15;
            Bs[kk][nn] = Wp[(size_t)(n0 + nn) * kC + (k0 + kk)];
        }
        __syncthreads();
        #pragma unroll
        for (int kk = 0; kk < BK; kk++) {
            float a[4], bb[4];
            #pragma unroll
            for (int i = 0; i < 4; i++) a[i] = As[kk][ty * 4 + i];
            #pragma unroll
            for (int j = 0; j < 4; j++) bb[j] = Bs[kk][tx * 4 + j];
            #pragma unroll
            for (int i = 0; i < 4; i++)
                #pragma unroll
                for (int j = 0; j < 4; j++) acc[i][j] += a[i] * bb[j];
        }
        __syncthreads();
    }
    #pragma unroll
    for (int i = 0; i < 4; i++) {
        int m = m0 + ty * 4 + i;
        #pragma unroll
        for (int j = 0; j < 4; j++) {
            int n = n0 + tx * 4 + j;
            out[(size_t)m * kC + n] = acc[i][j] + bp[n];
        }
    }
}

// ---------------------------------------------------------------------------
// 2) MFMA GEMM: out = epi(A @ W^T + bias [+resid]).  A (MxK) f32 row-major,
//    W (NxK) f32 row-major.  bf16 fragments, fp32 accumulate.
//    Block 256 = 4 waves; tile 64x64; BK=32.  Wave w: rows w*16..w*16+15.
// ---------------------------------------------------------------------------
__global__ __launch_bounds__(256) void mfma_gemm(
    const float* __restrict__ A, const float* __restrict__ W,
    const float* __restrict__ bias, const float* __restrict__ resid,
    float* __restrict__ out, int M, int Nout, int K, int epi)
{
    __shared__ __align__(16) short Asm[64][40];   // 32 data + 8 pad (16B-aligned rows)
    __shared__ __align__(16) short Bsm[64][40];

    const int tid = threadIdx.x;
    const int n0 = blockIdx.x * 64;
    const int m0 = blockIdx.y * 64;
    const int lane = tid & 63, wv = tid >> 6;
    const int lm = lane & 15, quad = lane >> 4;
    const int r = tid >> 2, q = tid & 3;          // staging: row r, k-quarter q

    float4v acc[4] = {};

    for (int k0 = 0; k0 < K; k0 += 32) {
        // stage A tile (64 x 32) and W tile (64 x 32) as bf16
        {
            const float* ap = A + (size_t)(m0 + r) * K + k0 + q * 8;
            short8 av;
            #pragma unroll
            for (int j = 0; j < 8; j++) av[j] = f2b(ap[j]);
            *(short8*)&Asm[r][q * 8] = av;
            const float* wp = W + (size_t)(n0 + r) * K + k0 + q * 8;
            short8 bv;
            #pragma unroll
            for (int j = 0; j < 8; j++) bv[j] = f2b(wp[j]);
            *(short8*)&Bsm[r][q * 8] = bv;
        }
        __syncthreads();

        short8 af = *(const short8*)&Asm[wv * 16 + lm][quad * 8];
        #pragma unroll
        for (int j4 = 0; j4 < 4; j4++) {
            short8 bf = *(const short8*)&Bsm[j4 * 16 + lm][quad * 8];
            acc[j4] = __builtin_amdgcn_mfma_f32_16x16x32_bf16(af, bf, acc[j4], 0, 0, 0);
        }
        __syncthreads();
    }

    #pragma unroll
    for (int j4 = 0; j4 < 4; j4++) {
        const int n = n0 + j4 * 16 + lm;
        const float bn = bias[n];
        #pragma unroll
        for (int rg = 0; rg < 4; rg++) {
            const int m = m0 + wv * 16 + quad * 4 + rg;
            float v = acc[j4][rg] + bn;
            if (resid) v += resid[(size_t)m * Nout + n];
            if (epi == 1) v = gelu_erf(v);
            out[(size_t)m * Nout + n] = v;
        }
    }
}

// ---------------------------------------------------------------------------
// 3) LayerNorm over C=256, one block per row, in place.
// ---------------------------------------------------------------------------
__global__ __launch_bounds__(256) void ln_kernel(
    float* __restrict__ x, const float* __restrict__ g, const float* __restrict__ bb)
{
    const size_t row = blockIdx.x;
    const int t = threadIdx.x;
    float v = x[row * kC + t];

    __shared__ float red4[4];
    float s = v;
    #pragma unroll
    for (int off = 32; off; off >>= 1) s += __shfl_xor(s, off, 64);
    if ((t & 63) == 0) red4[t >> 6] = s;
    __syncthreads();
    float mean = (red4[0] + red4[1] + red4[2] + red4[3]) * (1.0f / kC);

    float d = v - mean;
    float s2 = d * d;
    #pragma unroll
    for (int off = 32; off; off >>= 1) s2 += __shfl_xor(s2, off, 64);
    __syncthreads();
    if ((t & 63) == 0) red4[t >> 6] = s2;
    __syncthreads();
    float var = (red4[0] + red4[1] + red4[2] + red4[3]) * (1.0f / kC);

    float r = 1.0f / sqrtf(var + 1e-5f);
    x[row * kC + t] = d * r * g[t] + bb[t];
}

// ---------------------------------------------------------------------------
// 4) wave-per-query KNN: block = 8 waves = 8 queries; barrier-free selection.
//    512 threads -> 4 blocks/CU (LDS-limited) x 8 waves = 32 waves/CU (100%).
//    __launch_bounds__(512,8) caps VGPR at 64 so occupancy holds.
//    Identical strict-IEEE distance expression as before => same selection.
//    Scan is branchless with 4 independent min-chains; combining chains in
//    ascending-m order with strict < preserves the serial tie-break exactly.
// ---------------------------------------------------------------------------
__global__ __launch_bounds__(512, 8) void knn_kernel(
    const float* __restrict__ pos,
    const float* __restrict__ Wr1, const float* __restrict__ br1,
    const float* __restrict__ Wr2, const float* __restrict__ br2,
    int* __restrict__ idx_out, float* __restrict__ bias_out)
{
    __shared__ float px[kN], py[kN], pz[kN], sq[kN];
    __shared__ int selS[8][kKNN];

    const int b = blockIdx.y;
    const int t = threadIdx.x;
    const int lane = t & 63, wv = t >> 6;
    const int n = blockIdx.x * 8 + wv;

    const float* pb = pos + (size_t)b * 3 * kN;
    for (int m = t; m < kN; m += 512) {
        float x = pb[m], y = pb[kN + m], z = pb[2 * kN + m];
        px[m] = x; py[m] = y; pz[m] = z;
        sq[m] = __fadd_rn(__fadd_rn(__fmul_rn(x, x), __fmul_rn(y, y)), __fmul_rn(z, z));
    }
    __syncthreads();

    const float qx = px[n], qy = py[n], qz = pz[n], qsq = sq[n];

    // candidate m = c*64 + lane, c = 0..31
    float cd[32];
    #pragma unroll
    for (int c = 0; c < 32; c++) {
        int m = c * 64 + lane;
        float dot = __fadd_rn(__fadd_rn(__fmul_rn(qx, px[m]), __fmul_rn(qy, py[m])),
                              __fmul_rn(qz, pz[m]));
        cd[c] = __fsub_rn(__fadd_rn(qsq, sq[m]), __fmul_rn(2.0f, dot));
    }

    unsigned mask = 0;
    for (int r = 0; r < kKNN; r++) {
        // branchless 4-chain local min (chains ordered by ascending m range)
        float b0 = 1e30f, b1 = 1e30f, b2 = 1e30f, b3 = 1e30f;
        int i0 = kN, i1 = kN, i2 = kN, i3 = kN;
        #pragma unroll
        for (int c = 0; c < 8; c++) {
            float d0 = (mask & (1u << c))        ? 1e30f : cd[c];
            float d1 = (mask & (1u << (c + 8)))  ? 1e30f : cd[c + 8];
            float d2 = (mask & (1u << (c + 16))) ? 1e30f : cd[c + 16];
            float d3 = (mask & (1u << (c + 24))) ? 1e30f : cd[c + 24];
            if (d0 < b0) { b0 = d0; i0 = c * 64 + lane; }
            if (d1 < b1) { b1 = d1; i1 = (c + 8) * 64 + lane; }
            if (d2 < b2) { b2 = d2; i2 = (c + 16) * 64 + lane; }
            if (d3 < b3) { b3 = d3; i3 = (c + 24) * 64 + lane; }
        }
        if (b1 < b0) { b0 = b1; i0 = i1; }   // ties keep lower chain = smaller m
        if (b2 < b0) { b0 = b2; i0 = i2; }
        if (b3 < b0) { b0 = b3; i0 = i3; }
        float best = b0; int bid = i0;

        // wave butterfly lex-min (no barriers)
        #pragma unroll
        for (int off = 1; off < 64; off <<= 1) {
            float od = __shfl_xor(best, off, 64);
            int   oi = __shfl_xor(bid, off, 64);
            if (od < best || (od == best && oi < bid)) { best = od; bid = oi; }
        }
        if (lane == 0) selS[wv][r] = bid;
        if ((bid & 63) == lane) mask |= 1u << (bid >> 6);
    }

    // bias MLP: lane = (neighbor k = lane>>2, quarter part = lane&3)
    const int k = lane >> 2;
    const int part = lane & 3;
    const int m = selS[wv][k];
    const float rx = qx - px[m], ry = qy - py[m], rz = qz - pz[m];
    float partial = 0.0f;
    #pragma unroll
    for (int jj = 0; jj < 16; jj++) {
        int o = part * 16 + jj;
        float h = rx * Wr1[o * 3 + 0] + ry * Wr1[o * 3 + 1] +
                  rz * Wr1[o * 3 + 2] + br1[o];
        partial += gelu_erf(h) * Wr2[o];
    }
    partial += __shfl_xor(partial, 1, 64);
    partial += __shfl_xor(partial, 2, 64);
    if (part == 0) {
        size_t o = ((size_t)b * kN + n) * kKNN + k;
        idx_out[o] = m;
        bias_out[o] = partial + br2[0];
    }
}

// ---------------------------------------------------------------------------
// 5) sparse attention: block = (n, b), 4 waves = 4 heads, lane = d.
// ---------------------------------------------------------------------------
__global__ __launch_bounds__(256) void attn_kernel(
    const float* __restrict__ q, const float* __restrict__ kbuf,
    const float* __restrict__ vbuf, const int* __restrict__ idx,
    const float* __restrict__ bias, float* __restrict__ obuf)
{
    const int n = blockIdx.x;
    const int b = blockIdx.y;
    const int t = threadIdx.x;
    const int h = t >> 6;
    const int d = t & 63;

    const size_t row = (size_t)b * kN + n;
    const float qv = q[row * kC + h * kDH + d];

    __shared__ int   sidx[kKNN];
    __shared__ float sb[kKNN];
    if (t < kKNN) { sidx[t] = idx[row * kKNN + t]; sb[t] = bias[row * kKNN + t]; }
    __syncthreads();

    float sc[kKNN];
    #pragma unroll
    for (int j = 0; j < kKNN; j++) {
        size_t kr = (size_t)b * kN + sidx[j];
        float p = qv * kbuf[kr * kC + h * kDH + d];
        #pragma unroll
        for (int off = 32; off; off >>= 1) p += __shfl_xor(p, off, 64);
        sc[j] = p * 0.125f + sb[j];
    }
    float mx = sc[0];
    #pragma unroll
    for (int j = 1; j < kKNN; j++) mx = fmaxf(mx, sc[j]);
    float den = 0.0f;
    #pragma unroll
    for (int j = 0; j < kKNN; j++) { sc[j] = expf(sc[j] - mx); den += sc[j]; }
    const float inv = 1.0f / den;
    float o = 0.0f;
    #pragma unroll
    for (int j = 0; j < kKNN; j++) {
        size_t kr = (size_t)b * kN + sidx[j];
        o += sc[j] * inv * vbuf[kr * kC + h * kDH + d];
    }
    obuf[row * kC + h * kDH + d] = o;
}

// ---------------------------------------------------------------------------
// 6) LDS-tiled transpose (b,n,c) f32 -> (b,c,n) f32 out.
// ---------------------------------------------------------------------------
__global__ __launch_bounds__(256) void transpose_f32(
    const float* __restrict__ z, float* __restrict__ out)
{
    __shared__ float tile[32][33];
    const int b = blockIdx.z;
    const int n0 = blockIdx.x * 32;
    const int c0 = blockIdx.y * 32;
    const int tx = threadIdx.x;   // 32
    const int ty = threadIdx.y;   // 8
    #pragma unroll
    for (int i = 0; i < 32; i += 8)
        tile[ty + i][tx] = z[(size_t)b * kN * kC + (size_t)(n0 + ty + i) * kC + (c0 + tx)];
    __syncthreads();
    #pragma unroll
    for (int i = 0; i < 32; i += 8)
        out[(size_t)b * kC * kN + (size_t)(c0 + ty + i) * kN + (n0 + tx)] =
            tile[tx][ty + i];
}

// ---------------------------------------------------------------------------
extern "C" void kernel_launch(void* const* d_in, const int* in_sizes, int n_in,
                              void* d_out, int out_size, void* d_ws, size_t ws_size,
                              hipStream_t stream)
{
    const float* src1 = (const float*)d_in[0];
    const float* src2 = (const float*)d_in[1];
    const float* pos  = (const float*)d_in[2];
    const float* Wp   = (const float*)d_in[3];
    const float* bp   = (const float*)d_in[4];
    const float* Wr1  = (const float*)d_in[5];
    const float* br1  = (const float*)d_in[6];
    const float* Wr2  = (const float*)d_in[7];
    const float* br2  = (const float*)d_in[8];
    const float* Wqkv = (const float*)d_in[9];
    const float* bqkv = (const float*)d_in[10];
    const float* Wo   = (const float*)d_in[11];
    const float* bo   = (const float*)d_in[12];
    const float* g13  = (const float*)d_in[13];
    const float* b13  = (const float*)d_in[14];
    const float* g12  = (const float*)d_in[15];
    const float* b12  = (const float*)d_in[16];
    const float* W1   = (const float*)d_in[17];
    const float* b1   = (const float*)d_in[18];
    const float* W2   = (const float*)d_in[19];
    const float* b2   = (const float*)d_in[20];
    float* out = (float*)d_out;                      // fp32 output (b,c,n)

    const size_t S = (size_t)kB * kN * kC;  // 2,097,152 floats
    float* ws = (float*)d_ws;
    float* x1 = ws;            // LN13(s1); resid for out-proj
    float* x2 = ws + S;
    float* qb = ws + 2 * S;
    float* kb = ws + 3 * S;
    float* vb = ws + 4 * S;
    float* ob = ws + 5 * S;
    float* yb = ws + 6 * S;    // LN12 result; FFN input + resid
    float* hb = ws + 2 * S;    // alias qb..ob (dead by FFN1): 4S floats
    float* zb = ws + S;        // alias x2 (dead after v-projection)
    int*   idxb  = (int*)(ws + 7 * S);
    float* biasb = ws + 7 * S + (size_t)kB * kN * kKNN;

    const int M = kB * kN;  // 8192

    // 1) input projections
    proj_gemm<<<dim3(kC / 64, kN / 64, 8), 256, 0, stream>>>(src1, src2, Wp, bp, x1, x2);

    // 2) LN13 in place (x1 and x2 are contiguous -> one launch covers both)
    ln_kernel<<<2 * M, 256, 0, stream>>>(x1, g13, b13);

    // 3) KNN + rel-pos bias (wave-per-query, 8 queries/block)
    knn_kernel<<<dim3(kN / 8, kB), 512, 0, stream>>>(pos, Wr1, br1, Wr2, br2, idxb, biasb);

    // 4) q/k/v projections (MFMA)
    mfma_gemm<<<dim3(kC / 64, M / 64), 256, 0, stream>>>(x1, Wqkv, bqkv, nullptr, qb, M, kC, kC, 0);
    mfma_gemm<<<dim3(kC / 64, M / 64), 256, 0, stream>>>(x2, Wqkv + (size_t)kC * kC, bqkv + kC,
                                                         nullptr, kb, M, kC, kC, 0);
    mfma_gemm<<<dim3(kC / 64, M / 64), 256, 0, stream>>>(x2, Wqkv + (size_t)2 * kC * kC, bqkv + 2 * kC,
                                                         nullptr, vb, M, kC, kC, 0);

    // 5) sparse attention
    attn_kernel<<<dim3(kN, kB), 256, 0, stream>>>(qb, kb, vb, idxb, biasb, ob);

    // 6) out-proj + residual(x1), then LN12  (MFMA)
    mfma_gemm<<<dim3(kC / 64, M / 64), 256, 0, stream>>>(ob, Wo, bo, x1, yb, M, kC, kC, 0);
    ln_kernel<<<M, 256, 0, stream>>>(yb, g12, b12);

    // 7) FFN (MFMA)
    mfma_gemm<<<dim3(kDFF / 64, M / 64), 256, 0, stream>>>(yb, W1, b1, nullptr, hb, M, kDFF, kC, 1);
    mfma_gemm<<<dim3(kC / 64, M / 64), 256, 0, stream>>>(hb, W2, b2, yb, zb, M, kC, kDFF, 0);

    // 8) transpose to (b,c,n), fp32
    transpose_f32<<<dim3(kN / 32, kC / 32, kB), dim3(32, 8), 0, stream>>>(zb, out);
}

// Round 2
// 385.505 us; speedup vs baseline: 1.1605x; 1.0589x over previous
//
#include <hip/hip_runtime.h>
#include <hip/hip_bf16.h>
#include <math.h>

// Problem constants
constexpr int kB = 4;
constexpr int kN = 2048;
constexpr int kC = 256;
constexpr int kDFF = 1024;
constexpr int kKNN = 16;
constexpr int kDH = 64;

typedef __attribute__((ext_vector_type(8))) short short8;
typedef __attribute__((ext_vector_type(4))) float float4v;

__device__ __forceinline__ float gelu_erf(float x) {
    return 0.5f * x * (1.0f + erff(x * 0.70710678118654752440f));
}

// fp32 -> bf16 bits, round-to-nearest-even (bit-exact with HW conversion)
__device__ __forceinline__ short f2b(float f) {
    unsigned u = __float_as_uint(f);
    u = u + 0x7FFFu + ((u >> 16) & 1u);
    return (short)(u >> 16);
}

// ---------------------------------------------------------------------------
// 1) input_proj tiled fp32 (src is K-major; only 2 GF -- stays on vector ALU)
// ---------------------------------------------------------------------------
__global__ __launch_bounds__(256) void proj_gemm(
    const float* __restrict__ src1, const float* __restrict__ src2,
    const float* __restrict__ Wp, const float* __restrict__ bp,
    float* __restrict__ x1, float* __restrict__ x2)
{
    constexpr int BM = 64, BN = 64, BK = 16;
    __shared__ float As[BK][BM + 1];
    __shared__ float Bs[BK][BN + 1];

    const int z = blockIdx.z;
    const int b = z & 3;
    const float* A = (z < 4 ? src1 : src2) + (size_t)b * kC * kN;  // (C x N)
    float* out = (z < 4 ? x1 : x2) + (size_t)b * kN * kC;

    const int tid = threadIdx.x;
    const int n0 = blockIdx.x * BN;
    const int m0 = blockIdx.y * BM;
    const int tx = tid & 15, ty = tid >> 4;

    float acc[4][4] = {};
    for (int k0 = 0; k0 < kC; k0 += BK) {
        #pragma unroll
        for (int q = 0; q < 4; q++) {
            int e = tid + q * 256;
            int kk = e >> 6, mm = e & 63;
            As[kk][mm] = A[(size_t)(k0 + kk) * kN + (m0 + mm)];
        }
        #pragma unroll
        for (int q = 0; q < 4; q++) {
            int e = tid + q * 256;
            int nn = e >> 4, kk = e & 15;
            Bs[kk][nn] = Wp[(size_t)(n0 + nn) * kC + (k0 + kk)];
        }
        __syncthreads();
        #pragma unroll
        for (int kk = 0; kk < BK; kk++) {
            float a[4], bb[4];
            #pragma unroll
            for (int i = 0; i < 4; i++) a[i] = As[kk][ty * 4 + i];
            #pragma unroll
            for (int j = 0; j < 4; j++) bb[j] = Bs[kk][tx * 4 + j];
            #pragma unroll
            for (int i = 0; i < 4; i++)
                #pragma unroll
                for (int j = 0; j < 4; j++) acc[i][j] += a[i] * bb[j];
        }
        __syncthreads();
    }
    #pragma unroll
    for (int i = 0; i < 4; i++) {
        int m = m0 + ty * 4 + i;
        #pragma unroll
        for (int j = 0; j < 4; j++) {
            int n = n0 + tx * 4 + j;
            out[(size_t)m * kC + n] = acc[i][j] + bp[n];
        }
    }
}

// ---------------------------------------------------------------------------
// 2) MFMA GEMM: out = epi(A @ W^T + bias [+resid]).  A (MxK) f32 row-major,
//    W (NxK) f32 row-major.  bf16 fragments, fp32 accumulate.
//    Block 256 = 4 waves; tile 64x64; BK=32.  Wave w: rows w*16..w*16+15.
// ---------------------------------------------------------------------------
__global__ __launch_bounds__(256) void mfma_gemm(
    const float* __restrict__ A, const float* __restrict__ W,
    const float* __restrict__ bias, const float* __restrict__ resid,
    float* __restrict__ out, int M, int Nout, int K, int epi)
{
    __shared__ __align__(16) short Asm[64][40];   // 32 data + 8 pad (16B-aligned rows)
    __shared__ __align__(16) short Bsm[64][40];

    const int tid = threadIdx.x;
    const int n0 = blockIdx.x * 64;
    const int m0 = blockIdx.y * 64;
    const int lane = tid & 63, wv = tid >> 6;
    const int lm = lane & 15, quad = lane >> 4;
    const int r = tid >> 2, q = tid & 3;          // staging: row r, k-quarter q

    float4v acc[4] = {};

    for (int k0 = 0; k0 < K; k0 += 32) {
        // stage A tile (64 x 32) and W tile (64 x 32) as bf16
        {
            const float* ap = A + (size_t)(m0 + r) * K + k0 + q * 8;
            short8 av;
            #pragma unroll
            for (int j = 0; j < 8; j++) av[j] = f2b(ap[j]);
            *(short8*)&Asm[r][q * 8] = av;
            const float* wp = W + (size_t)(n0 + r) * K + k0 + q * 8;
            short8 bv;
            #pragma unroll
            for (int j = 0; j < 8; j++) bv[j] = f2b(wp[j]);
            *(short8*)&Bsm[r][q * 8] = bv;
        }
        __syncthreads();

        short8 af = *(const short8*)&Asm[wv * 16 + lm][quad * 8];
        #pragma unroll
        for (int j4 = 0; j4 < 4; j4++) {
            short8 bf = *(const short8*)&Bsm[j4 * 16 + lm][quad * 8];
            acc[j4] = __builtin_amdgcn_mfma_f32_16x16x32_bf16(af, bf, acc[j4], 0, 0, 0);
        }
        __syncthreads();
    }

    #pragma unroll
    for (int j4 = 0; j4 < 4; j4++) {
        const int n = n0 + j4 * 16 + lm;
        const float bn = bias[n];
        #pragma unroll
        for (int rg = 0; rg < 4; rg++) {
            const int m = m0 + wv * 16 + quad * 4 + rg;
            float v = acc[j4][rg] + bn;
            if (resid) v += resid[(size_t)m * Nout + n];
            if (epi == 1) v = gelu_erf(v);
            out[(size_t)m * Nout + n] = v;
        }
    }
}

// ---------------------------------------------------------------------------
// 3) LayerNorm over C=256, one block per row, in place.
// ---------------------------------------------------------------------------
__global__ __launch_bounds__(256) void ln_kernel(
    float* __restrict__ x, const float* __restrict__ g, const float* __restrict__ bb)
{
    const size_t row = blockIdx.x;
    const int t = threadIdx.x;
    float v = x[row * kC + t];

    __shared__ float red4[4];
    float s = v;
    #pragma unroll
    for (int off = 32; off; off >>= 1) s += __shfl_xor(s, off, 64);
    if ((t & 63) == 0) red4[t >> 6] = s;
    __syncthreads();
    float mean = (red4[0] + red4[1] + red4[2] + red4[3]) * (1.0f / kC);

    float d = v - mean;
    float s2 = d * d;
    #pragma unroll
    for (int off = 32; off; off >>= 1) s2 += __shfl_xor(s2, off, 64);
    __syncthreads();
    if ((t & 63) == 0) red4[t >> 6] = s2;
    __syncthreads();
    float var = (red4[0] + red4[1] + red4[2] + red4[3]) * (1.0f / kC);

    float r = 1.0f / sqrtf(var + 1e-5f);
    x[row * kC + t] = d * r * g[t] + bb[t];
}

// ---------------------------------------------------------------------------
// 4) wave-per-query KNN: block = 8 waves = 8 queries; barrier-free selection.
//    LDS = 3*8KB (px,py,pz) + 512B = 25,088 B -> 6 blocks/CU by LDS.
//    NO min-waves in launch_bounds: forcing 8 waves/EU spilled cd[32] to
//    scratch (52 MB HBM traffic, R1 post-mortem). Natural VGPR ~52-60 gives
//    8 waves/SIMD without spill. sq recomputed inline with the identical
//    strict-IEEE expression => bit-identical selection.
// ---------------------------------------------------------------------------
__global__ __launch_bounds__(512) void knn_kernel(
    const float* __restrict__ pos,
    const float* __restrict__ Wr1, const float* __restrict__ br1,
    const float* __restrict__ Wr2, const float* __restrict__ br2,
    int* __restrict__ idx_out, float* __restrict__ bias_out)
{
    __shared__ float px[kN], py[kN], pz[kN];
    __shared__ int selS[8][kKNN];

    const int b = blockIdx.y;
    const int t = threadIdx.x;
    const int lane = t & 63, wv = t >> 6;
    const int n = blockIdx.x * 8 + wv;

    const float* pb = pos + (size_t)b * 3 * kN;
    for (int m = t; m < kN; m += 512) {
        px[m] = pb[m]; py[m] = pb[kN + m]; pz[m] = pb[2 * kN + m];
    }
    __syncthreads();

    const float qx = px[n], qy = py[n], qz = pz[n];
    const float qsq = __fadd_rn(__fadd_rn(__fmul_rn(qx, qx), __fmul_rn(qy, qy)),
                                __fmul_rn(qz, qz));

    // candidate m = c*64 + lane, c = 0..31
    float cd[32];
    #pragma unroll
    for (int c = 0; c < 32; c++) {
        int m = c * 64 + lane;
        float ax = px[m], ay = py[m], az = pz[m];
        float asq = __fadd_rn(__fadd_rn(__fmul_rn(ax, ax), __fmul_rn(ay, ay)),
                              __fmul_rn(az, az));
        float dot = __fadd_rn(__fadd_rn(__fmul_rn(qx, ax), __fmul_rn(qy, ay)),
                              __fmul_rn(qz, az));
        cd[c] = __fsub_rn(__fadd_rn(qsq, asq), __fmul_rn(2.0f, dot));
    }

    unsigned mask = 0;
    for (int r = 0; r < kKNN; r++) {
        // branchless 4-chain local min (chains ordered by ascending m range)
        float b0 = 1e30f, b1 = 1e30f, b2 = 1e30f, b3 = 1e30f;
        int i0 = kN, i1 = kN, i2 = kN, i3 = kN;
        #pragma unroll
        for (int c = 0; c < 8; c++) {
            float d0 = (mask & (1u << c))        ? 1e30f : cd[c];
            float d1 = (mask & (1u << (c + 8)))  ? 1e30f : cd[c + 8];
            float d2 = (mask & (1u << (c + 16))) ? 1e30f : cd[c + 16];
            float d3 = (mask & (1u << (c + 24))) ? 1e30f : cd[c + 24];
            if (d0 < b0) { b0 = d0; i0 = c * 64 + lane; }
            if (d1 < b1) { b1 = d1; i1 = (c + 8) * 64 + lane; }
            if (d2 < b2) { b2 = d2; i2 = (c + 16) * 64 + lane; }
            if (d3 < b3) { b3 = d3; i3 = (c + 24) * 64 + lane; }
        }
        if (b1 < b0) { b0 = b1; i0 = i1; }   // ties keep lower chain = smaller m
        if (b2 < b0) { b0 = b2; i0 = i2; }
        if (b3 < b0) { b0 = b3; i0 = i3; }
        float best = b0; int bid = i0;

        // wave butterfly lex-min (no barriers)
        #pragma unroll
        for (int off = 1; off < 64; off <<= 1) {
            float od = __shfl_xor(best, off, 64);
            int   oi = __shfl_xor(bid, off, 64);
            if (od < best || (od == best && oi < bid)) { best = od; bid = oi; }
        }
        if (lane == 0) selS[wv][r] = bid;
        if ((bid & 63) == lane) mask |= 1u << (bid >> 6);
    }

    // bias MLP: lane = (neighbor k = lane>>2, quarter part = lane&3)
    const int k = lane >> 2;
    const int part = lane & 3;
    const int m = selS[wv][k];
    const float rx = qx - px[m], ry = qy - py[m], rz = qz - pz[m];
    float partial = 0.0f;
    #pragma unroll
    for (int jj = 0; jj < 16; jj++) {
        int o = part * 16 + jj;
        float h = rx * Wr1[o * 3 + 0] + ry * Wr1[o * 3 + 1] +
                  rz * Wr1[o * 3 + 2] + br1[o];
        partial += gelu_erf(h) * Wr2[o];
    }
    partial += __shfl_xor(partial, 1, 64);
    partial += __shfl_xor(partial, 2, 64);
    if (part == 0) {
        size_t o = ((size_t)b * kN + n) * kKNN + k;
        idx_out[o] = m;
        bias_out[o] = partial + br2[0];
    }
}

// ---------------------------------------------------------------------------
// 5) sparse attention: block = (n, b), 4 waves = 4 heads, lane = d.
//    kv buffer is fused k|v with row stride 512 (k at +0, v at +256).
// ---------------------------------------------------------------------------
__global__ __launch_bounds__(256) void attn_kernel(
    const float* __restrict__ q, const float* __restrict__ kv,
    const int* __restrict__ idx, const float* __restrict__ bias,
    float* __restrict__ obuf)
{
    const int n = blockIdx.x;
    const int b = blockIdx.y;
    const int t = threadIdx.x;
    const int h = t >> 6;
    const int d = t & 63;

    const size_t row = (size_t)b * kN + n;
    const float qv = q[row * kC + h * kDH + d];

    __shared__ int   sidx[kKNN];
    __shared__ float sb[kKNN];
    if (t < kKNN) { sidx[t] = idx[row * kKNN + t]; sb[t] = bias[row * kKNN + t]; }
    __syncthreads();

    float sc[kKNN];
    #pragma unroll
    for (int j = 0; j < kKNN; j++) {
        size_t kr = (size_t)b * kN + sidx[j];
        float p = qv * kv[kr * 512 + h * kDH + d];
        #pragma unroll
        for (int off = 32; off; off >>= 1) p += __shfl_xor(p, off, 64);
        sc[j] = p * 0.125f + sb[j];
    }
    float mx = sc[0];
    #pragma unroll
    for (int j = 1; j < kKNN; j++) mx = fmaxf(mx, sc[j]);
    float den = 0.0f;
    #pragma unroll
    for (int j = 0; j < kKNN; j++) { sc[j] = expf(sc[j] - mx); den += sc[j]; }
    const float inv = 1.0f / den;
    float o = 0.0f;
    #pragma unroll
    for (int j = 0; j < kKNN; j++) {
        size_t kr = (size_t)b * kN + sidx[j];
        o += sc[j] * inv * kv[kr * 512 + kC + h * kDH + d];
    }
    obuf[row * kC + h * kDH + d] = o;
}

// ---------------------------------------------------------------------------
// 6) LDS-tiled transpose (b,n,c) f32 -> (b,c,n) f32 out.
// ---------------------------------------------------------------------------
__global__ __launch_bounds__(256) void transpose_f32(
    const float* __restrict__ z, float* __restrict__ out)
{
    __shared__ float tile[32][33];
    const int b = blockIdx.z;
    const int n0 = blockIdx.x * 32;
    const int c0 = blockIdx.y * 32;
    const int tx = threadIdx.x;   // 32
    const int ty = threadIdx.y;   // 8
    #pragma unroll
    for (int i = 0; i < 32; i += 8)
        tile[ty + i][tx] = z[(size_t)b * kN * kC + (size_t)(n0 + ty + i) * kC + (c0 + tx)];
    __syncthreads();
    #pragma unroll
    for (int i = 0; i < 32; i += 8)
        out[(size_t)b * kC * kN + (size_t)(c0 + ty + i) * kN + (n0 + tx)] =
            tile[tx][ty + i];
}

// ---------------------------------------------------------------------------
extern "C" void kernel_launch(void* const* d_in, const int* in_sizes, int n_in,
                              void* d_out, int out_size, void* d_ws, size_t ws_size,
                              hipStream_t stream)
{
    const float* src1 = (const float*)d_in[0];
    const float* src2 = (const float*)d_in[1];
    const float* pos  = (const float*)d_in[2];
    const float* Wp   = (const float*)d_in[3];
    const float* bp   = (const float*)d_in[4];
    const float* Wr1  = (const float*)d_in[5];
    const float* br1  = (const float*)d_in[6];
    const float* Wr2  = (const float*)d_in[7];
    const float* br2  = (const float*)d_in[8];
    const float* Wqkv = (const float*)d_in[9];
    const float* bqkv = (const float*)d_in[10];
    const float* Wo   = (const float*)d_in[11];
    const float* bo   = (const float*)d_in[12];
    const float* g13  = (const float*)d_in[13];
    const float* b13  = (const float*)d_in[14];
    const float* g12  = (const float*)d_in[15];
    const float* b12  = (const float*)d_in[16];
    const float* W1   = (const float*)d_in[17];
    const float* b1   = (const float*)d_in[18];
    const float* W2   = (const float*)d_in[19];
    const float* b2   = (const float*)d_in[20];
    float* out = (float*)d_out;                      // fp32 output (b,c,n)

    const size_t S = (size_t)kB * kN * kC;  // 2,097,152 floats
    float* ws = (float*)d_ws;
    float* x1 = ws;            // LN13(s1); resid for out-proj
    float* x2 = ws + S;
    float* qb = ws + 2 * S;
    float* kvb = ws + 3 * S;   // fused k|v, row stride 512: 2S floats
    float* ob = ws + 5 * S;
    float* yb = ws + 6 * S;    // LN12 result; FFN input + resid
    float* hb = ws + 2 * S;    // alias qb..ob (dead by FFN1): 4S floats
    float* zb = ws + S;        // alias x2 (dead after kv-projection)
    int*   idxb  = (int*)(ws + 7 * S);
    float* biasb = ws + 7 * S + (size_t)kB * kN * kKNN;

    const int M = kB * kN;  // 8192

    // 1) input projections
    proj_gemm<<<dim3(kC / 64, kN / 64, 8), 256, 0, stream>>>(src1, src2, Wp, bp, x1, x2);

    // 2) LN13 in place (x1 and x2 are contiguous -> one launch covers both)
    ln_kernel<<<2 * M, 256, 0, stream>>>(x1, g13, b13);

    // 3) KNN + rel-pos bias (wave-per-query, 8 queries/block)
    knn_kernel<<<dim3(kN / 8, kB), 512, 0, stream>>>(pos, Wr1, br1, Wr2, br2, idxb, biasb);

    // 4) q projection; fused k|v projection (Wk,Wv are contiguous rows of Wqkv)
    mfma_gemm<<<dim3(kC / 64, M / 64), 256, 0, stream>>>(x1, Wqkv, bqkv, nullptr, qb, M, kC, kC, 0);
    mfma_gemm<<<dim3(2 * kC / 64, M / 64), 256, 0, stream>>>(x2, Wqkv + (size_t)kC * kC, bqkv + kC,
                                                             nullptr, kvb, M, 2 * kC, kC, 0);

    // 5) sparse attention
    attn_kernel<<<dim3(kN, kB), 256, 0, stream>>>(qb, kvb, idxb, biasb, ob);

    // 6) out-proj + residual(x1), then LN12  (MFMA)
    mfma_gemm<<<dim3(kC / 64, M / 64), 256, 0, stream>>>(ob, Wo, bo, x1, yb, M, kC, kC, 0);
    ln_kernel<<<M, 256, 0, stream>>>(yb, g12, b12);

    // 7) FFN (MFMA)
    mfma_gemm<<<dim3(kDFF / 64, M / 64), 256, 0, stream>>>(yb, W1, b1, nullptr, hb, M, kDFF, kC, 1);
    mfma_gemm<<<dim3(kC / 64, M / 64), 256, 0, stream>>>(hb, W2, b2, yb, zb, M, kC, kDFF, 0);

    // 8) transpose to (b,c,n), fp32
    transpose_f32<<<dim3(kN / 32, kC / 32, kB), dim3(32, 8), 0, stream>>>(zb, out);
}

// Round 3
// 351.516 us; speedup vs baseline: 1.2727x; 1.0967x over previous
//
#include <hip/hip_runtime.h>
#include <hip/hip_bf16.h>
#include <math.h>

// Problem constants
constexpr int kB = 4;
constexpr int kN = 2048;
constexpr int kC = 256;
constexpr int kDFF = 1024;
constexpr int kKNN = 16;
constexpr int kDH = 64;

typedef __attribute__((ext_vector_type(8))) short short8;
typedef __attribute__((ext_vector_type(4))) float float4v;

__device__ __forceinline__ float gelu_erf(float x) {
    return 0.5f * x * (1.0f + erff(x * 0.70710678118654752440f));
}

// fp32 -> bf16 bits, round-to-nearest-even (bit-exact with HW conversion)
__device__ __forceinline__ short f2b(float f) {
    unsigned u = __float_as_uint(f);
    u = u + 0x7FFFu + ((u >> 16) & 1u);
    return (short)(u >> 16);
}

// ---------------------------------------------------------------------------
// 0) one-shot weight conversion f32 -> bf16 into contiguous workspace block:
//    [Wqkv 196608][Wo 65536][W1 262144][W2 262144]  (all counts % 8 == 0)
// ---------------------------------------------------------------------------
__global__ __launch_bounds__(256) void cvt_weights(
    const float* __restrict__ Wqkv, const float* __restrict__ Wo,
    const float* __restrict__ W1, const float* __restrict__ W2,
    short* __restrict__ dst)
{
    const int i = (blockIdx.x * 256 + threadIdx.x) * 8;
    const float* src; int off;
    if (i < 196608)      { src = Wqkv; off = i; }
    else if (i < 262144) { src = Wo;   off = i - 196608; }
    else if (i < 524288) { src = W1;   off = i - 262144; }
    else                 { src = W2;   off = i - 524288; }
    short8 v;
    #pragma unroll
    for (int j = 0; j < 8; j++) v[j] = f2b(src[off + j]);
    *(short8*)&dst[i] = v;
}

// ---------------------------------------------------------------------------
// 1) input_proj tiled fp32 (src is K-major; only 2 GF -- stays on vector ALU)
// ---------------------------------------------------------------------------
__global__ __launch_bounds__(256) void proj_gemm(
    const float* __restrict__ src1, const float* __restrict__ src2,
    const float* __restrict__ Wp, const float* __restrict__ bp,
    float* __restrict__ x1, float* __restrict__ x2)
{
    constexpr int BM = 64, BN = 64, BK = 16;
    __shared__ float As[BK][BM + 1];
    __shared__ float Bs[BK][BN + 1];

    const int z = blockIdx.z;
    const int b = z & 3;
    const float* A = (z < 4 ? src1 : src2) + (size_t)b * kC * kN;  // (C x N)
    float* out = (z < 4 ? x1 : x2) + (size_t)b * kN * kC;

    const int tid = threadIdx.x;
    const int n0 = blockIdx.x * BN;
    const int m0 = blockIdx.y * BM;
    const int tx = tid & 15, ty = tid >> 4;

    float acc[4][4] = {};
    for (int k0 = 0; k0 < kC; k0 += BK) {
        #pragma unroll
        for (int q = 0; q < 4; q++) {
            int e = tid + q * 256;
            int kk = e >> 6, mm = e & 63;
            As[kk][mm] = A[(size_t)(k0 + kk) * kN + (m0 + mm)];
        }
        #pragma unroll
        for (int q = 0; q < 4; q++) {
            int e = tid + q * 256;
            int nn = e >> 4, kk = e & 15;
            Bs[kk][nn] = Wp[(size_t)(n0 + nn) * kC + (k0 + kk)];
        }
        __syncthreads();
        #pragma unroll
        for (int kk = 0; kk < BK; kk++) {
            float a[4], bb[4];
            #pragma unroll
            for (int i = 0; i < 4; i++) a[i] = As[kk][ty * 4 + i];
            #pragma unroll
            for (int j = 0; j < 4; j++) bb[j] = Bs[kk][tx * 4 + j];
            #pragma unroll
            for (int i = 0; i < 4; i++)
                #pragma unroll
                for (int j = 0; j < 4; j++) acc[i][j] += a[i] * bb[j];
        }
        __syncthreads();
    }
    #pragma unroll
    for (int i = 0; i < 4; i++) {
        int m = m0 + ty * 4 + i;
        #pragma unroll
        for (int j = 0; j < 4; j++) {
            int n = n0 + tx * 4 + j;
            out[(size_t)m * kC + n] = acc[i][j] + bp[n];
        }
    }
}

// ---------------------------------------------------------------------------
// 2) MFMA GEMM, bf16 inputs: out = epi(A @ W^T + bias [+resid]).
//    A (MxK) bf16 row-major, W (NxK) bf16 row-major; fp32 accumulate.
//    Staging is a single 16B bf16 load + ds_write_b128 per operand per
//    thread (no f32->bf16 conversion in the hot loop -- that was the
//    VALU bottleneck of the previous version).
// ---------------------------------------------------------------------------
__global__ __launch_bounds__(256) void mfma_gemm_bf(
    const short* __restrict__ A, const short* __restrict__ W,
    const float* __restrict__ bias, const float* __restrict__ resid,
    float* __restrict__ out, short* __restrict__ outbf,
    int M, int Nout, int K, int epi)
{
    __shared__ __align__(16) short Asm[64][40];   // 32 data + 8 pad (16B rows)
    __shared__ __align__(16) short Bsm[64][40];

    const int tid = threadIdx.x;
    const int n0 = blockIdx.x * 64;
    const int m0 = blockIdx.y * 64;
    const int lane = tid & 63, wv = tid >> 6;
    const int lm = lane & 15, quad = lane >> 4;
    const int r = tid >> 2, q = tid & 3;          // staging: row r, k-quarter q

    float4v acc[4] = {};

    for (int k0 = 0; k0 < K; k0 += 32) {
        *(short8*)&Asm[r][q * 8] = *(const short8*)&A[(size_t)(m0 + r) * K + k0 + q * 8];
        *(short8*)&Bsm[r][q * 8] = *(const short8*)&W[(size_t)(n0 + r) * K + k0 + q * 8];
        __syncthreads();

        short8 af = *(const short8*)&Asm[wv * 16 + lm][quad * 8];
        #pragma unroll
        for (int j4 = 0; j4 < 4; j4++) {
            short8 bf = *(const short8*)&Bsm[j4 * 16 + lm][quad * 8];
            acc[j4] = __builtin_amdgcn_mfma_f32_16x16x32_bf16(af, bf, acc[j4], 0, 0, 0);
        }
        __syncthreads();
    }

    #pragma unroll
    for (int j4 = 0; j4 < 4; j4++) {
        const int n = n0 + j4 * 16 + lm;
        const float bn = bias[n];
        #pragma unroll
        for (int rg = 0; rg < 4; rg++) {
            const int m = m0 + wv * 16 + quad * 4 + rg;
            float v = acc[j4][rg] + bn;
            if (resid) v += resid[(size_t)m * Nout + n];
            if (epi == 1) v = gelu_erf(v);
            if (out)   out[(size_t)m * Nout + n] = v;
            if (outbf) outbf[(size_t)m * Nout + n] = f2b(v);
        }
    }
}

// ---------------------------------------------------------------------------
// 3) LayerNorm over C=256, one block per row, in place; also emits bf16 copy.
// ---------------------------------------------------------------------------
__global__ __launch_bounds__(256) void ln_kernel(
    float* __restrict__ x, short* __restrict__ xbf,
    const float* __restrict__ g, const float* __restrict__ bb)
{
    const size_t row = blockIdx.x;
    const int t = threadIdx.x;
    float v = x[row * kC + t];

    __shared__ float red4[4];
    float s = v;
    #pragma unroll
    for (int off = 32; off; off >>= 1) s += __shfl_xor(s, off, 64);
    if ((t & 63) == 0) red4[t >> 6] = s;
    __syncthreads();
    float mean = (red4[0] + red4[1] + red4[2] + red4[3]) * (1.0f / kC);

    float d = v - mean;
    float s2 = d * d;
    #pragma unroll
    for (int off = 32; off; off >>= 1) s2 += __shfl_xor(s2, off, 64);
    __syncthreads();
    if ((t & 63) == 0) red4[t >> 6] = s2;
    __syncthreads();
    float var = (red4[0] + red4[1] + red4[2] + red4[3]) * (1.0f / kC);

    float r = 1.0f / sqrtf(var + 1e-5f);
    float o = d * r * g[t] + bb[t];
    x[row * kC + t] = o;
    xbf[row * kC + t] = f2b(o);
}

// ---------------------------------------------------------------------------
// 4) wave-per-query KNN: block = 8 waves = 8 queries; barrier-free selection.
//    VALU-issue-bound at 83% (R2); restructure deferred. Unchanged.
// ---------------------------------------------------------------------------
__global__ __launch_bounds__(512) void knn_kernel(
    const float* __restrict__ pos,
    const float* __restrict__ Wr1, const float* __restrict__ br1,
    const float* __restrict__ Wr2, const float* __restrict__ br2,
    int* __restrict__ idx_out, float* __restrict__ bias_out)
{
    __shared__ float px[kN], py[kN], pz[kN];
    __shared__ int selS[8][kKNN];

    const int b = blockIdx.y;
    const int t = threadIdx.x;
    const int lane = t & 63, wv = t >> 6;
    const int n = blockIdx.x * 8 + wv;

    const float* pb = pos + (size_t)b * 3 * kN;
    for (int m = t; m < kN; m += 512) {
        px[m] = pb[m]; py[m] = pb[kN + m]; pz[m] = pb[2 * kN + m];
    }
    __syncthreads();

    const float qx = px[n], qy = py[n], qz = pz[n];
    const float qsq = __fadd_rn(__fadd_rn(__fmul_rn(qx, qx), __fmul_rn(qy, qy)),
                                __fmul_rn(qz, qz));

    // candidate m = c*64 + lane, c = 0..31
    float cd[32];
    #pragma unroll
    for (int c = 0; c < 32; c++) {
        int m = c * 64 + lane;
        float ax = px[m], ay = py[m], az = pz[m];
        float asq = __fadd_rn(__fadd_rn(__fmul_rn(ax, ax), __fmul_rn(ay, ay)),
                              __fmul_rn(az, az));
        float dot = __fadd_rn(__fadd_rn(__fmul_rn(qx, ax), __fmul_rn(qy, ay)),
                              __fmul_rn(qz, az));
        cd[c] = __fsub_rn(__fadd_rn(qsq, asq), __fmul_rn(2.0f, dot));
    }

    unsigned mask = 0;
    for (int r = 0; r < kKNN; r++) {
        // branchless 4-chain local min (chains ordered by ascending m range)
        float b0 = 1e30f, b1 = 1e30f, b2 = 1e30f, b3 = 1e30f;
        int i0 = kN, i1 = kN, i2 = kN, i3 = kN;
        #pragma unroll
        for (int c = 0; c < 8; c++) {
            float d0 = (mask & (1u << c))        ? 1e30f : cd[c];
            float d1 = (mask & (1u << (c + 8)))  ? 1e30f : cd[c + 8];
            float d2 = (mask & (1u << (c + 16))) ? 1e30f : cd[c + 16];
            float d3 = (mask & (1u << (c + 24))) ? 1e30f : cd[c + 24];
            if (d0 < b0) { b0 = d0; i0 = c * 64 + lane; }
            if (d1 < b1) { b1 = d1; i1 = (c + 8) * 64 + lane; }
            if (d2 < b2) { b2 = d2; i2 = (c + 16) * 64 + lane; }
            if (d3 < b3) { b3 = d3; i3 = (c + 24) * 64 + lane; }
        }
        if (b1 < b0) { b0 = b1; i0 = i1; }   // ties keep lower chain = smaller m
        if (b2 < b0) { b0 = b2; i0 = i2; }
        if (b3 < b0) { b0 = b3; i0 = i3; }
        float best = b0; int bid = i0;

        // wave butterfly lex-min (no barriers)
        #pragma unroll
        for (int off = 1; off < 64; off <<= 1) {
            float od = __shfl_xor(best, off, 64);
            int   oi = __shfl_xor(bid, off, 64);
            if (od < best || (od == best && oi < bid)) { best = od; bid = oi; }
        }
        if (lane == 0) selS[wv][r] = bid;
        if ((bid & 63) == lane) mask |= 1u << (bid >> 6);
    }

    // bias MLP: lane = (neighbor k = lane>>2, quarter part = lane&3)
    const int k = lane >> 2;
    const int part = lane & 3;
    const int m = selS[wv][k];
    const float rx = qx - px[m], ry = qy - py[m], rz = qz - pz[m];
    float partial = 0.0f;
    #pragma unroll
    for (int jj = 0; jj < 16; jj++) {
        int o = part * 16 + jj;
        float h = rx * Wr1[o * 3 + 0] + ry * Wr1[o * 3 + 1] +
                  rz * Wr1[o * 3 + 2] + br1[o];
        partial += gelu_erf(h) * Wr2[o];
    }
    partial += __shfl_xor(partial, 1, 64);
    partial += __shfl_xor(partial, 2, 64);
    if (part == 0) {
        size_t o = ((size_t)b * kN + n) * kKNN + k;
        idx_out[o] = m;
        bias_out[o] = partial + br2[0];
    }
}

// ---------------------------------------------------------------------------
// 5) sparse attention: block = (n, b), 4 waves = 4 heads, lane = d.
//    kv buffer is fused k|v with row stride 512 (k at +0, v at +256).
//    Output written directly as bf16 (only consumer is out-proj GEMM A).
// ---------------------------------------------------------------------------
__global__ __launch_bounds__(256) void attn_kernel(
    const float* __restrict__ q, const float* __restrict__ kv,
    const int* __restrict__ idx, const float* __restrict__ bias,
    short* __restrict__ obf)
{
    const int n = blockIdx.x;
    const int b = blockIdx.y;
    const int t = threadIdx.x;
    const int h = t >> 6;
    const int d = t & 63;

    const size_t row = (size_t)b * kN + n;
    const float qv = q[row * kC + h * kDH + d];

    __shared__ int   sidx[kKNN];
    __shared__ float sb[kKNN];
    if (t < kKNN) { sidx[t] = idx[row * kKNN + t]; sb[t] = bias[row * kKNN + t]; }
    __syncthreads();

    float sc[kKNN];
    #pragma unroll
    for (int j = 0; j < kKNN; j++) {
        size_t kr = (size_t)b * kN + sidx[j];
        float p = qv * kv[kr * 512 + h * kDH + d];
        #pragma unroll
        for (int off = 32; off; off >>= 1) p += __shfl_xor(p, off, 64);
        sc[j] = p * 0.125f + sb[j];
    }
    float mx = sc[0];
    #pragma unroll
    for (int j = 1; j < kKNN; j++) mx = fmaxf(mx, sc[j]);
    float den = 0.0f;
    #pragma unroll
    for (int j = 0; j < kKNN; j++) { sc[j] = expf(sc[j] - mx); den += sc[j]; }
    const float inv = 1.0f / den;
    float o = 0.0f;
    #pragma unroll
    for (int j = 0; j < kKNN; j++) {
        size_t kr = (size_t)b * kN + sidx[j];
        o += sc[j] * inv * kv[kr * 512 + kC + h * kDH + d];
    }
    obf[row * kC + h * kDH + d] = f2b(o);
}

// ---------------------------------------------------------------------------
// 6) LDS-tiled transpose (b,n,c) f32 -> (b,c,n) f32 out.
// ---------------------------------------------------------------------------
__global__ __launch_bounds__(256) void transpose_f32(
    const float* __restrict__ z, float* __restrict__ out)
{
    __shared__ float tile[32][33];
    const int b = blockIdx.z;
    const int n0 = blockIdx.x * 32;
    const int c0 = blockIdx.y * 32;
    const int tx = threadIdx.x;   // 32
    const int ty = threadIdx.y;   // 8
    #pragma unroll
    for (int i = 0; i < 32; i += 8)
        tile[ty + i][tx] = z[(size_t)b * kN * kC + (size_t)(n0 + ty + i) * kC + (c0 + tx)];
    __syncthreads();
    #pragma unroll
    for (int i = 0; i < 32; i += 8)
        out[(size_t)b * kC * kN + (size_t)(c0 + ty + i) * kN + (n0 + tx)] =
            tile[tx][ty + i];
}

// ---------------------------------------------------------------------------
extern "C" void kernel_launch(void* const* d_in, const int* in_sizes, int n_in,
                              void* d_out, int out_size, void* d_ws, size_t ws_size,
                              hipStream_t stream)
{
    const float* src1 = (const float*)d_in[0];
    const float* src2 = (const float*)d_in[1];
    const float* pos  = (const float*)d_in[2];
    const float* Wp   = (const float*)d_in[3];
    const float* bp   = (const float*)d_in[4];
    const float* Wr1  = (const float*)d_in[5];
    const float* br1  = (const float*)d_in[6];
    const float* Wr2  = (const float*)d_in[7];
    const float* br2  = (const float*)d_in[8];
    const float* Wqkv = (const float*)d_in[9];
    const float* bqkv = (const float*)d_in[10];
    const float* Wo   = (const float*)d_in[11];
    const float* bo   = (const float*)d_in[12];
    const float* g13  = (const float*)d_in[13];
    const float* b13  = (const float*)d_in[14];
    const float* g12  = (const float*)d_in[15];
    const float* b12  = (const float*)d_in[16];
    const float* W1   = (const float*)d_in[17];
    const float* b1   = (const float*)d_in[18];
    const float* W2   = (const float*)d_in[19];
    const float* b2   = (const float*)d_in[20];
    float* out = (float*)d_out;                      // fp32 output (b,c,n)

    const size_t S = (size_t)kB * kN * kC;  // 2,097,152 floats
    float* ws = (float*)d_ws;
    // f32 buffers
    float* x1  = ws;             // proj s1 out; LN13 in place; resid for out-proj
    float* s2  = ws + S;         // proj s2 out (f32 dead after LN13); zb aliases
    float* qb  = ws + 2 * S;     // q f32; yb aliases after attn
    float* kvb = ws + 3 * S;     // fused k|v f32, row stride 512 (2S); hbf aliases
    float* yb  = ws + 2 * S;     // alias qb (dead after attn)
    float* zb  = ws + S;         // alias s2 (dead after LN13)
    // bf16 buffers (as shorts)
    short* x1bf = (short*)(ws + 5 * S);              // S shorts  [5S, 5.5S)
    short* x2bf = (short*)(ws + 5 * S) + S;          // S shorts  [5.5S, 6S)
    short* ybf  = (short*)(ws + 6 * S);              // S shorts  [6S, 6.5S)
    short* obf  = (short*)(ws + 6 * S) + S;          // S shorts  [6.5S, 7S)
    short* hbf  = (short*)(ws + 3 * S);              // alias kvb: 4S shorts (M x DFF)
    // knn outputs
    int*   idxb  = (int*)(ws + 7 * S);
    float* biasb = ws + 7 * S + (size_t)kB * kN * kKNN;
    // bf16 weights (contiguous): [qkv][o][w1][w2]
    short* wbf    = (short*)(ws + 7 * S + 2 * (size_t)kB * kN * kKNN);
    short* Wqkvbf = wbf;                  // 196608 shorts
    short* Wobf   = wbf + 196608;         // 65536
    short* W1bf   = wbf + 262144;         // 262144
    short* W2bf   = wbf + 524288;         // 262144

    const int M = kB * kN;  // 8192

    // 0) weight conversion (one-time per launch; independent of data path)
    cvt_weights<<<384, 256, 0, stream>>>(Wqkv, Wo, W1, W2, wbf);

    // 1) input projections (f32 out; LN needs f32 input)
    proj_gemm<<<dim3(kC / 64, kN / 64, 8), 256, 0, stream>>>(src1, src2, Wp, bp, x1, s2);

    // 2) LN13: x1,s2 contiguous; x1bf,x2bf contiguous -> one launch
    ln_kernel<<<2 * M, 256, 0, stream>>>(x1, x1bf, g13, b13);

    // 3) KNN + rel-pos bias
    knn_kernel<<<dim3(kN / 8, kB), 512, 0, stream>>>(pos, Wr1, br1, Wr2, br2, idxb, biasb);

    // 4) q projection; fused k|v projection (Wk,Wv contiguous rows of Wqkv)
    mfma_gemm_bf<<<dim3(kC / 64, M / 64), 256, 0, stream>>>(
        x1bf, Wqkvbf, bqkv, nullptr, qb, nullptr, M, kC, kC, 0);
    mfma_gemm_bf<<<dim3(2 * kC / 64, M / 64), 256, 0, stream>>>(
        x2bf, Wqkvbf + (size_t)kC * kC, bqkv + kC, nullptr, kvb, nullptr, M, 2 * kC, kC, 0);

    // 5) sparse attention (bf16 out)
    attn_kernel<<<dim3(kN, kB), 256, 0, stream>>>(qb, kvb, idxb, biasb, obf);

    // 6) out-proj + residual(x1), then LN12
    mfma_gemm_bf<<<dim3(kC / 64, M / 64), 256, 0, stream>>>(
        obf, Wobf, bo, x1, yb, nullptr, M, kC, kC, 0);
    ln_kernel<<<M, 256, 0, stream>>>(yb, ybf, g12, b12);

    // 7) FFN: ffn1 writes bf16 only (sole consumer is ffn2 A); ffn2 f32+resid
    mfma_gemm_bf<<<dim3(kDFF / 64, M / 64), 256, 0, stream>>>(
        ybf, W1bf, b1, nullptr, nullptr, hbf, M, kDFF, kC, 1);
    mfma_gemm_bf<<<dim3(kC / 64, M / 64), 256, 0, stream>>>(
        hbf, W2bf, b2, yb, zb, nullptr, M, kC, kDFF, 0);

    // 8) transpose to (b,c,n), fp32
    transpose_f32<<<dim3(kN / 32, kC / 32, kB), dim3(32, 8), 0, stream>>>(zb, out);
}

// Round 5
// 337.528 us; speedup vs baseline: 1.3254x; 1.0414x over previous
//
#include <hip/hip_runtime.h>
#include <hip/hip_bf16.h>
#include <math.h>

// Problem constants
constexpr int kB = 4;
constexpr int kN = 2048;
constexpr int kC = 256;
constexpr int kDFF = 1024;
constexpr int kKNN = 16;
constexpr int kDH = 64;

typedef __attribute__((ext_vector_type(8))) short short8;
typedef __attribute__((ext_vector_type(4))) float float4v;

__device__ __forceinline__ float gelu_erf(float x) {
    return 0.5f * x * (1.0f + erff(x * 0.70710678118654752440f));
}

// fp32 -> bf16 bits, round-to-nearest-even (bit-exact with HW conversion)
__device__ __forceinline__ short f2b(float f) {
    unsigned u = __float_as_uint(f);
    u = u + 0x7FFFu + ((u >> 16) & 1u);
    return (short)(u >> 16);
}

// ---------------------------------------------------------------------------
// 0) one-shot weight conversion f32 -> bf16 into contiguous workspace block:
//    [Wqkv 196608][Wo 65536][W1 262144][W2 262144]  (all counts % 8 == 0)
// ---------------------------------------------------------------------------
__global__ __launch_bounds__(256) void cvt_weights(
    const float* __restrict__ Wqkv, const float* __restrict__ Wo,
    const float* __restrict__ W1, const float* __restrict__ W2,
    short* __restrict__ dst)
{
    const int i = (blockIdx.x * 256 + threadIdx.x) * 8;
    const float* src; int off;
    if (i < 196608)      { src = Wqkv; off = i; }
    else if (i < 262144) { src = Wo;   off = i - 196608; }
    else if (i < 524288) { src = W1;   off = i - 262144; }
    else                 { src = W2;   off = i - 524288; }
    short8 v;
    #pragma unroll
    for (int j = 0; j < 8; j++) v[j] = f2b(src[off + j]);
    *(short8*)&dst[i] = v;
}

// ---------------------------------------------------------------------------
// 1) input_proj tiled fp32 (src is K-major; only 2 GF -- stays on vector ALU)
// ---------------------------------------------------------------------------
__global__ __launch_bounds__(256) void proj_gemm(
    const float* __restrict__ src1, const float* __restrict__ src2,
    const float* __restrict__ Wp, const float* __restrict__ bp,
    float* __restrict__ x1, float* __restrict__ x2)
{
    constexpr int BM = 64, BN = 64, BK = 16;
    __shared__ float As[BK][BM + 1];
    __shared__ float Bs[BK][BN + 1];

    const int z = blockIdx.z;
    const int b = z & 3;
    const float* A = (z < 4 ? src1 : src2) + (size_t)b * kC * kN;  // (C x N)
    float* out = (z < 4 ? x1 : x2) + (size_t)b * kN * kC;

    const int tid = threadIdx.x;
    const int n0 = blockIdx.x * BN;
    const int m0 = blockIdx.y * BM;
    const int tx = tid & 15, ty = tid >> 4;

    float acc[4][4] = {};
    for (int k0 = 0; k0 < kC; k0 += BK) {
        #pragma unroll
        for (int q = 0; q < 4; q++) {
            int e = tid + q * 256;
            int kk = e >> 6, mm = e & 63;
            As[kk][mm] = A[(size_t)(k0 + kk) * kN + (m0 + mm)];
        }
        #pragma unroll
        for (int q = 0; q < 4; q++) {
            int e = tid + q * 256;
            int nn = e >> 4, kk = e & 15;
            Bs[kk][nn] = Wp[(size_t)(n0 + nn) * kC + (k0 + kk)];
        }
        __syncthreads();
        #pragma unroll
        for (int kk = 0; kk < BK; kk++) {
            float a[4], bb[4];
            #pragma unroll
            for (int i = 0; i < 4; i++) a[i] = As[kk][ty * 4 + i];
            #pragma unroll
            for (int j = 0; j < 4; j++) bb[j] = Bs[kk][tx * 4 + j];
            #pragma unroll
            for (int i = 0; i < 4; i++)
                #pragma unroll
                for (int j = 0; j < 4; j++) acc[i][j] += a[i] * bb[j];
        }
        __syncthreads();
    }
    #pragma unroll
    for (int i = 0; i < 4; i++) {
        int m = m0 + ty * 4 + i;
        #pragma unroll
        for (int j = 0; j < 4; j++) {
            int n = n0 + tx * 4 + j;
            out[(size_t)m * kC + n] = acc[i][j] + bp[n];
        }
    }
}

// ---------------------------------------------------------------------------
// 2) MFMA GEMM, bf16 inputs: out = epi(A @ W^T + bias [+resid]).
//    A (MxK) bf16 row-major, W (NxK) bf16 row-major; fp32 accumulate.
// ---------------------------------------------------------------------------
__global__ __launch_bounds__(256) void mfma_gemm_bf(
    const short* __restrict__ A, const short* __restrict__ W,
    const float* __restrict__ bias, const float* __restrict__ resid,
    float* __restrict__ out, short* __restrict__ outbf,
    int M, int Nout, int K, int epi)
{
    __shared__ __align__(16) short Asm[64][40];   // 32 data + 8 pad (16B rows)
    __shared__ __align__(16) short Bsm[64][40];

    const int tid = threadIdx.x;
    const int n0 = blockIdx.x * 64;
    const int m0 = blockIdx.y * 64;
    const int lane = tid & 63, wv = tid >> 6;
    const int lm = lane & 15, quad = lane >> 4;
    const int r = tid >> 2, q = tid & 3;          // staging: row r, k-quarter q

    float4v acc[4] = {};

    for (int k0 = 0; k0 < K; k0 += 32) {
        *(short8*)&Asm[r][q * 8] = *(const short8*)&A[(size_t)(m0 + r) * K + k0 + q * 8];
        *(short8*)&Bsm[r][q * 8] = *(const short8*)&W[(size_t)(n0 + r) * K + k0 + q * 8];
        __syncthreads();

        short8 af = *(const short8*)&Asm[wv * 16 + lm][quad * 8];
        #pragma unroll
        for (int j4 = 0; j4 < 4; j4++) {
            short8 bf = *(const short8*)&Bsm[j4 * 16 + lm][quad * 8];
            acc[j4] = __builtin_amdgcn_mfma_f32_16x16x32_bf16(af, bf, acc[j4], 0, 0, 0);
        }
        __syncthreads();
    }

    #pragma unroll
    for (int j4 = 0; j4 < 4; j4++) {
        const int n = n0 + j4 * 16 + lm;
        const float bn = bias[n];
        #pragma unroll
        for (int rg = 0; rg < 4; rg++) {
            const int m = m0 + wv * 16 + quad * 4 + rg;
            float v = acc[j4][rg] + bn;
            if (resid) v += resid[(size_t)m * Nout + n];
            if (epi == 1) v = gelu_erf(v);
            if (out)   out[(size_t)m * Nout + n] = v;
            if (outbf) outbf[(size_t)m * Nout + n] = f2b(v);
        }
    }
}

// ---------------------------------------------------------------------------
// 3) LayerNorm over C=256, one block per row, in place; also emits bf16 copy.
// ---------------------------------------------------------------------------
__global__ __launch_bounds__(256) void ln_kernel(
    float* __restrict__ x, short* __restrict__ xbf,
    const float* __restrict__ g, const float* __restrict__ bb)
{
    const size_t row = blockIdx.x;
    const int t = threadIdx.x;
    float v = x[row * kC + t];

    __shared__ float red4[4];
    float s = v;
    #pragma unroll
    for (int off = 32; off; off >>= 1) s += __shfl_xor(s, off, 64);
    if ((t & 63) == 0) red4[t >> 6] = s;
    __syncthreads();
    float mean = (red4[0] + red4[1] + red4[2] + red4[3]) * (1.0f / kC);

    float d = v - mean;
    float s2 = d * d;
    #pragma unroll
    for (int off = 32; off; off >>= 1) s2 += __shfl_xor(s2, off, 64);
    __syncthreads();
    if ((t & 63) == 0) red4[t >> 6] = s2;
    __syncthreads();
    float var = (red4[0] + red4[1] + red4[2] + red4[3]) * (1.0f / kC);

    float r = 1.0f / sqrtf(var + 1e-5f);
    float o = d * r * g[t] + bb[t];
    x[row * kC + t] = o;
    xbf[row * kC + t] = f2b(o);
}

// ---------------------------------------------------------------------------
// 4) wave-per-query KNN, tournament-tree selection.
//    Per-chain minima (bm0..3/bi0..3) are cached in registers; each round
//    invalidates exactly one element in one chain, and the winner bid is
//    wave-uniform -> readfirstlane(bid>>9) gives a SCALAR chain id, so a
//    uniform switch rescans only that chain (8 steps) instead of all 32.
//    Selection sequence provably identical to full rescan (strict-< scan
//    in ascending c, ascending-chain merge, lex butterfly all unchanged).
// ---------------------------------------------------------------------------
#define KNN_RESCAN(CH, BM, BI)                                        \
    do {                                                              \
        float nb_ = 1e30f; int ni_ = kN;                              \
        _Pragma("unroll")                                             \
        for (int c8_ = 0; c8_ < 8; c8_++) {                           \
            int c_ = (CH) * 8 + c8_;                                  \
            float dd_ = (mask & (1u << c_)) ? 1e30f : cd[c_];         \
            if (dd_ < nb_) { nb_ = dd_; ni_ = c_ * 64 + lane; }       \
        }                                                             \
        BM = nb_; BI = ni_;                                           \
    } while (0)

__global__ __launch_bounds__(512) void knn_kernel(
    const float* __restrict__ pos,
    const float* __restrict__ Wr1, const float* __restrict__ br1,
    const float* __restrict__ Wr2, const float* __restrict__ br2,
    int* __restrict__ idx_out, float* __restrict__ bias_out)
{
    __shared__ float px[kN], py[kN], pz[kN];
    __shared__ int selS[8][kKNN];

    const int b = blockIdx.y;
    const int t = threadIdx.x;
    const int lane = t & 63, wv = t >> 6;
    const int n = blockIdx.x * 8 + wv;

    const float* pb = pos + (size_t)b * 3 * kN;
    for (int m = t; m < kN; m += 512) {
        px[m] = pb[m]; py[m] = pb[kN + m]; pz[m] = pb[2 * kN + m];
    }
    __syncthreads();

    const float qx = px[n], qy = py[n], qz = pz[n];
    const float qsq = __fadd_rn(__fadd_rn(__fmul_rn(qx, qx), __fmul_rn(qy, qy)),
                                __fmul_rn(qz, qz));

    // distances + initial per-chain minima (mask empty here); 4 chains give
    // 4 independent FLOP dep-chains. Ascending c8 within chain preserves
    // the first-minimum (smallest m) tie-break of a serial ascending scan.
    float cd[32];
    float bm0 = 1e30f, bm1 = 1e30f, bm2 = 1e30f, bm3 = 1e30f;
    int bi0 = kN, bi1 = kN, bi2 = kN, bi3 = kN;
    #pragma unroll
    for (int c8 = 0; c8 < 8; c8++) {
        {
            const int c = c8, m = c * 64 + lane;
            float ax = px[m], ay = py[m], az = pz[m];
            float asq = __fadd_rn(__fadd_rn(__fmul_rn(ax, ax), __fmul_rn(ay, ay)), __fmul_rn(az, az));
            float dot = __fadd_rn(__fadd_rn(__fmul_rn(qx, ax), __fmul_rn(qy, ay)), __fmul_rn(qz, az));
            float d = __fsub_rn(__fadd_rn(qsq, asq), __fmul_rn(2.0f, dot));
            cd[c] = d;
            if (d < bm0) { bm0 = d; bi0 = m; }
        }
        {
            const int c = c8 + 8, m = c * 64 + lane;
            float ax = px[m], ay = py[m], az = pz[m];
            float asq = __fadd_rn(__fadd_rn(__fmul_rn(ax, ax), __fmul_rn(ay, ay)), __fmul_rn(az, az));
            float dot = __fadd_rn(__fadd_rn(__fmul_rn(qx, ax), __fmul_rn(qy, ay)), __fmul_rn(qz, az));
            float d = __fsub_rn(__fadd_rn(qsq, asq), __fmul_rn(2.0f, dot));
            cd[c] = d;
            if (d < bm1) { bm1 = d; bi1 = m; }
        }
        {
            const int c = c8 + 16, m = c * 64 + lane;
            float ax = px[m], ay = py[m], az = pz[m];
            float asq = __fadd_rn(__fadd_rn(__fmul_rn(ax, ax), __fmul_rn(ay, ay)), __fmul_rn(az, az));
            float dot = __fadd_rn(__fadd_rn(__fmul_rn(qx, ax), __fmul_rn(qy, ay)), __fmul_rn(qz, az));
            float d = __fsub_rn(__fadd_rn(qsq, asq), __fmul_rn(2.0f, dot));
            cd[c] = d;
            if (d < bm2) { bm2 = d; bi2 = m; }
        }
        {
            const int c = c8 + 24, m = c * 64 + lane;
            float ax = px[m], ay = py[m], az = pz[m];
            float asq = __fadd_rn(__fadd_rn(__fmul_rn(ax, ax), __fmul_rn(ay, ay)), __fmul_rn(az, az));
            float dot = __fadd_rn(__fadd_rn(__fmul_rn(qx, ax), __fmul_rn(qy, ay)), __fmul_rn(qz, az));
            float d = __fsub_rn(__fadd_rn(qsq, asq), __fmul_rn(2.0f, dot));
            cd[c] = d;
            if (d < bm3) { bm3 = d; bi3 = m; }
        }
    }

    unsigned mask = 0;
    for (int r = 0; r < kKNN; r++) {
        // merge cached chain minima (ties keep lower chain = smaller m)
        float best = bm0; int bid = bi0;
        if (bm1 < best) { best = bm1; bid = bi1; }
        if (bm2 < best) { best = bm2; bid = bi2; }
        if (bm3 < best) { best = bm3; bid = bi3; }

        // wave butterfly lex-min (no barriers)
        #pragma unroll
        for (int off = 1; off < 64; off <<= 1) {
            float od = __shfl_xor(best, off, 64);
            int   oi = __shfl_xor(bid, off, 64);
            if (od < best || (od == best && oi < bid)) { best = od; bid = oi; }
        }
        if (lane == 0) selS[wv][r] = bid;
        if ((bid & 63) == lane) mask |= 1u << (bid >> 6);

        if (r < kKNN - 1) {
            // bid is wave-uniform; rescan ONLY the winner's chain (scalar branch)
            const int sch = __builtin_amdgcn_readfirstlane(bid >> 9);
            switch (sch) {
                case 0:  KNN_RESCAN(0, bm0, bi0); break;
                case 1:  KNN_RESCAN(1, bm1, bi1); break;
                case 2:  KNN_RESCAN(2, bm2, bi2); break;
                default: KNN_RESCAN(3, bm3, bi3); break;
            }
        }
    }

    // bias MLP: lane = (neighbor k = lane>>2, quarter part = lane&3)
    const int k = lane >> 2;
    const int part = lane & 3;
    const int m = selS[wv][k];
    const float rx = qx - px[m], ry = qy - py[m], rz = qz - pz[m];
    float partial = 0.0f;
    #pragma unroll
    for (int jj = 0; jj < 16; jj++) {
        int o = part * 16 + jj;
        float h = rx * Wr1[o * 3 + 0] + ry * Wr1[o * 3 + 1] +
                  rz * Wr1[o * 3 + 2] + br1[o];
        partial += gelu_erf(h) * Wr2[o];
    }
    partial += __shfl_xor(partial, 1, 64);
    partial += __shfl_xor(partial, 2, 64);
    if (part == 0) {
        size_t o = ((size_t)b * kN + n) * kKNN + k;
        idx_out[o] = m;
        bias_out[o] = partial + br2[0];
    }
}

// ---------------------------------------------------------------------------
// 5) sparse attention: block = (n, b), 4 waves = 4 heads, lane = d.
//    kv buffer is fused k|v with row stride 512 (k at +0, v at +256).
//    Output written directly as bf16 (only consumer is out-proj GEMM A).
// ---------------------------------------------------------------------------
__global__ __launch_bounds__(256) void attn_kernel(
    const float* __restrict__ q, const float* __restrict__ kv,
    const int* __restrict__ idx, const float* __restrict__ bias,
    short* __restrict__ obf)
{
    const int n = blockIdx.x;
    const int b = blockIdx.y;
    const int t = threadIdx.x;
    const int h = t >> 6;
    const int d = t & 63;

    const size_t row = (size_t)b * kN + n;
    const float qv = q[row * kC + h * kDH + d];

    __shared__ int   sidx[kKNN];
    __shared__ float sb[kKNN];
    if (t < kKNN) { sidx[t] = idx[row * kKNN + t]; sb[t] = bias[row * kKNN + t]; }
    __syncthreads();

    float sc[kKNN];
    #pragma unroll
    for (int j = 0; j < kKNN; j++) {
        size_t kr = (size_t)b * kN + sidx[j];
        float p = qv * kv[kr * 512 + h * kDH + d];
        #pragma unroll
        for (int off = 32; off; off >>= 1) p += __shfl_xor(p, off, 64);
        sc[j] = p * 0.125f + sb[j];
    }
    float mx = sc[0];
    #pragma unroll
    for (int j = 1; j < kKNN; j++) mx = fmaxf(mx, sc[j]);
    float den = 0.0f;
    #pragma unroll
    for (int j = 0; j < kKNN; j++) { sc[j] = expf(sc[j] - mx); den += sc[j]; }
    const float inv = 1.0f / den;
    float o = 0.0f;
    #pragma unroll
    for (int j = 0; j < kKNN; j++) {
        size_t kr = (size_t)b * kN + sidx[j];
        o += sc[j] * inv * kv[kr * 512 + kC + h * kDH + d];
    }
    obf[row * kC + h * kDH + d] = f2b(o);
}

// ---------------------------------------------------------------------------
// 6) LDS-tiled transpose (b,n,c) f32 -> (b,c,n) f32 out.
// ---------------------------------------------------------------------------
__global__ __launch_bounds__(256) void transpose_f32(
    const float* __restrict__ z, float* __restrict__ out)
{
    __shared__ float tile[32][33];
    const int b = blockIdx.z;
    const int n0 = blockIdx.x * 32;
    const int c0 = blockIdx.y * 32;
    const int tx = threadIdx.x;   // 32
    const int ty = threadIdx.y;   // 8
    #pragma unroll
    for (int i = 0; i < 32; i += 8)
        tile[ty + i][tx] = z[(size_t)b * kN * kC + (size_t)(n0 + ty + i) * kC + (c0 + tx)];
    __syncthreads();
    #pragma unroll
    for (int i = 0; i < 32; i += 8)
        out[(size_t)b * kC * kN + (size_t)(c0 + ty + i) * kN + (n0 + tx)] =
            tile[tx][ty + i];
}

// ---------------------------------------------------------------------------
extern "C" void kernel_launch(void* const* d_in, const int* in_sizes, int n_in,
                              void* d_out, int out_size, void* d_ws, size_t ws_size,
                              hipStream_t stream)
{
    const float* src1 = (const float*)d_in[0];
    const float* src2 = (const float*)d_in[1];
    const float* pos  = (const float*)d_in[2];
    const float* Wp   = (const float*)d_in[3];
    const float* bp   = (const float*)d_in[4];
    const float* Wr1  = (const float*)d_in[5];
    const float* br1  = (const float*)d_in[6];
    const float* Wr2  = (const float*)d_in[7];
    const float* br2  = (const float*)d_in[8];
    const float* Wqkv = (const float*)d_in[9];
    const float* bqkv = (const float*)d_in[10];
    const float* Wo   = (const float*)d_in[11];
    const float* bo   = (const float*)d_in[12];
    const float* g13  = (const float*)d_in[13];
    const float* b13  = (const float*)d_in[14];
    const float* g12  = (const float*)d_in[15];
    const float* b12  = (const float*)d_in[16];
    const float* W1   = (const float*)d_in[17];
    const float* b1   = (const float*)d_in[18];
    const float* W2   = (const float*)d_in[19];
    const float* b2   = (const float*)d_in[20];
    float* out = (float*)d_out;                      // fp32 output (b,c,n)

    const size_t S = (size_t)kB * kN * kC;  // 2,097,152 floats
    float* ws = (float*)d_ws;
    // f32 buffers
    float* x1  = ws;             // proj s1 out; LN13 in place; resid for out-proj
    float* s2  = ws + S;         // proj s2 out (f32 dead after LN13); zb aliases
    float* qb  = ws + 2 * S;     // q f32; yb aliases after attn
    float* kvb = ws + 3 * S;     // fused k|v f32, row stride 512 (2S); hbf aliases
    float* yb  = ws + 2 * S;     // alias qb (dead after attn)
    float* zb  = ws + S;         // alias s2 (dead after LN13)
    // bf16 buffers (as shorts)
    short* x1bf = (short*)(ws + 5 * S);              // S shorts  [5S, 5.5S)
    short* x2bf = (short*)(ws + 5 * S) + S;          // S shorts  [5.5S, 6S)
    short* ybf  = (short*)(ws + 6 * S);              // S shorts  [6S, 6.5S)
    short* obf  = (short*)(ws + 6 * S) + S;          // S shorts  [6.5S, 7S)
    short* hbf  = (short*)(ws + 3 * S);              // alias kvb: 4S shorts (M x DFF)
    // knn outputs
    int*   idxb  = (int*)(ws + 7 * S);
    float* biasb = ws + 7 * S + (size_t)kB * kN * kKNN;
    // bf16 weights (contiguous): [qkv][o][w1][w2]
    short* wbf    = (short*)(ws + 7 * S + 2 * (size_t)kB * kN * kKNN);
    short* Wqkvbf = wbf;                  // 196608 shorts
    short* Wobf   = wbf + 196608;         // 65536
    short* W1bf   = wbf + 262144;         // 262144
    short* W2bf   = wbf + 524288;         // 262144

    const int M = kB * kN;  // 8192

    // 0) weight conversion (one-time per launch; independent of data path)
    cvt_weights<<<384, 256, 0, stream>>>(Wqkv, Wo, W1, W2, wbf);

    // 1) input projections (f32 out; LN needs f32 input)
    proj_gemm<<<dim3(kC / 64, kN / 64, 8), 256, 0, stream>>>(src1, src2, Wp, bp, x1, s2);

    // 2) LN13: x1,s2 contiguous; x1bf,x2bf contiguous -> one launch
    ln_kernel<<<2 * M, 256, 0, stream>>>(x1, x1bf, g13, b13);

    // 3) KNN + rel-pos bias
    knn_kernel<<<dim3(kN / 8, kB), 512, 0, stream>>>(pos, Wr1, br1, Wr2, br2, idxb, biasb);

    // 4) q projection; fused k|v projection (Wk,Wv contiguous rows of Wqkv)
    mfma_gemm_bf<<<dim3(kC / 64, M / 64), 256, 0, stream>>>(
        x1bf, Wqkvbf, bqkv, nullptr, qb, nullptr, M, kC, kC, 0);
    mfma_gemm_bf<<<dim3(2 * kC / 64, M / 64), 256, 0, stream>>>(
        x2bf, Wqkvbf + (size_t)kC * kC, bqkv + kC, nullptr, kvb, nullptr, M, 2 * kC, kC, 0);

    // 5) sparse attention (bf16 out)
    attn_kernel<<<dim3(kN, kB), 256, 0, stream>>>(qb, kvb, idxb, biasb, obf);

    // 6) out-proj + residual(x1), then LN12
    mfma_gemm_bf<<<dim3(kC / 64, M / 64), 256, 0, stream>>>(
        obf, Wobf, bo, x1, yb, nullptr, M, kC, kC, 0);
    ln_kernel<<<M, 256, 0, stream>>>(yb, ybf, g12, b12);

    // 7) FFN: ffn1 writes bf16 only (sole consumer is ffn2 A); ffn2 f32+resid
    mfma_gemm_bf<<<dim3(kDFF / 64, M / 64), 256, 0, stream>>>(
        ybf, W1bf, b1, nullptr, nullptr, hbf, M, kDFF, kC, 1);
    mfma_gemm_bf<<<dim3(kC / 64, M / 64), 256, 0, stream>>>(
        hbf, W2bf, b2, yb, zb, nullptr, M, kC, kDFF, 0);

    // 8) transpose to (b,c,n), fp32
    transpose_f32<<<dim3(kN / 32, kC / 32, kB), dim3(32, 8), 0, stream>>>(zb, out);
}

// Round 6
// 310.593 us; speedup vs baseline: 1.4404x; 1.0867x over previous
//
#include <hip/hip_runtime.h>
#include <hip/hip_bf16.h>
#include <math.h>

// Problem constants
constexpr int kB = 4;
constexpr int kN = 2048;
constexpr int kC = 256;
constexpr int kDFF = 1024;
constexpr int kKNN = 16;
constexpr int kDH = 64;

typedef __attribute__((ext_vector_type(8))) short short8;
typedef __attribute__((ext_vector_type(4))) float float4v;

__device__ __forceinline__ float gelu_erf(float x) {
    return 0.5f * x * (1.0f + erff(x * 0.70710678118654752440f));
}

// fp32 -> bf16 bits, round-to-nearest-even (bit-exact with HW conversion)
__device__ __forceinline__ short f2b(float f) {
    unsigned u = __float_as_uint(f);
    u = u + 0x7FFFu + ((u >> 16) & 1u);
    return (short)(u >> 16);
}

// bf16 bits -> fp32 (exact)
__device__ __forceinline__ float b2f(short h) {
    unsigned u = ((unsigned)(unsigned short)h) << 16;
    return __uint_as_float(u);
}

// ---------------------------------------------------------------------------
// 0a) one-shot weight conversion f32 -> bf16 into contiguous workspace block:
//     [Wqkv 196608][Wo 65536][W1 262144][W2 262144]  (all counts % 8 == 0)
// ---------------------------------------------------------------------------
__global__ __launch_bounds__(256) void cvt_weights(
    const float* __restrict__ Wqkv, const float* __restrict__ Wo,
    const float* __restrict__ W1, const float* __restrict__ W2,
    short* __restrict__ dst)
{
    const int i = (blockIdx.x * 256 + threadIdx.x) * 8;
    const float* src; int off;
    if (i < 196608)      { src = Wqkv; off = i; }
    else if (i < 262144) { src = Wo;   off = i - 196608; }
    else if (i < 524288) { src = W1;   off = i - 262144; }
    else                 { src = W2;   off = i - 524288; }
    short8 v;
    #pragma unroll
    for (int j = 0; j < 8; j++) v[j] = f2b(src[off + j]);
    *(short8*)&dst[i] = v;
}

// ---------------------------------------------------------------------------
// 0b) Wp -> hi/lo bf16 split (v = hi + lo exactly to ~2^-18 rel).
//     65536 elements, 32 blocks.
// ---------------------------------------------------------------------------
__global__ __launch_bounds__(256) void cvt_wp(
    const float* __restrict__ Wp, short* __restrict__ hi, short* __restrict__ lo)
{
    const int i = (blockIdx.x * 256 + threadIdx.x) * 8;
    short8 h, l;
    #pragma unroll
    for (int j = 0; j < 8; j++) {
        float v = Wp[i + j];
        short hh = f2b(v);
        h[j] = hh;
        l[j] = f2b(v - b2f(hh));
    }
    *(short8*)&hi[i] = h;
    *(short8*)&lo[i] = l;
}

// ---------------------------------------------------------------------------
// 0c) src (b,C,N) f32 -> srcT (z,N,C) bf16 hi/lo, z = s*4+b (rows 0..16383).
//     32x32 LDS-tiled transpose; k-contiguous rows for MFMA A staging.
// ---------------------------------------------------------------------------
__global__ __launch_bounds__(256) void transpose_cvt(
    const float* __restrict__ src1, const float* __restrict__ src2,
    short* __restrict__ hiT, short* __restrict__ loT)
{
    __shared__ float tile[32][33];
    const int z = blockIdx.z;
    const float* in = (z < 4 ? src1 : src2) + (size_t)(z & 3) * kC * kN;
    const int n0 = blockIdx.x * 32;
    const int c0 = blockIdx.y * 32;
    const int tx = threadIdx.x;   // 32
    const int ty = threadIdx.y;   // 8
    #pragma unroll
    for (int i = 0; i < 32; i += 8)
        tile[ty + i][tx] = in[(size_t)(c0 + ty + i) * kN + (n0 + tx)];
    __syncthreads();
    #pragma unroll
    for (int i = 0; i < 32; i += 8) {
        float v = tile[tx][ty + i];                 // src[c0+tx][n0+ty+i]
        short h = f2b(v);
        short l = f2b(v - b2f(h));
        size_t o = ((size_t)z * kN + (n0 + ty + i)) * kC + (c0 + tx);
        hiT[o] = h;
        loT[o] = l;
    }
}

// ---------------------------------------------------------------------------
// 1) input_proj as bf16x3 MFMA GEMM (numerically ~f32: err ~2^-17 rel).
//    A = srcT hi/lo (16384 x 256), W = Wp hi/lo (256 x 256), out f32 row-major
//    (x1 then s2, contiguous).  Same 64x64-tile structure as mfma_gemm_bf,
//    3 MFMAs per fragment pair: Alo*Whi + Ahi*Wlo + Ahi*Whi.
// ---------------------------------------------------------------------------
__global__ __launch_bounds__(256) void proj_mfma(
    const short* __restrict__ Ahi, const short* __restrict__ Alo,
    const short* __restrict__ Whi, const short* __restrict__ Wlo,
    const float* __restrict__ bias, float* __restrict__ out)
{
    __shared__ __align__(16) short AsmH[64][40], AsmL[64][40];
    __shared__ __align__(16) short BsmH[64][40], BsmL[64][40];

    const int tid = threadIdx.x;
    const int n0 = blockIdx.x * 64;
    const size_t m0 = (size_t)blockIdx.y * 64;
    const int lane = tid & 63, wv = tid >> 6;
    const int lm = lane & 15, quad = lane >> 4;
    const int r = tid >> 2, q = tid & 3;

    float4v acc[4] = {};

    for (int k0 = 0; k0 < kC; k0 += 32) {
        *(short8*)&AsmH[r][q * 8] = *(const short8*)&Ahi[(m0 + r) * kC + k0 + q * 8];
        *(short8*)&AsmL[r][q * 8] = *(const short8*)&Alo[(m0 + r) * kC + k0 + q * 8];
        *(short8*)&BsmH[r][q * 8] = *(const short8*)&Whi[(size_t)(n0 + r) * kC + k0 + q * 8];
        *(short8*)&BsmL[r][q * 8] = *(const short8*)&Wlo[(size_t)(n0 + r) * kC + k0 + q * 8];
        __syncthreads();

        short8 ah = *(const short8*)&AsmH[wv * 16 + lm][quad * 8];
        short8 al = *(const short8*)&AsmL[wv * 16 + lm][quad * 8];
        #pragma unroll
        for (int j4 = 0; j4 < 4; j4++) {
            short8 bh = *(const short8*)&BsmH[j4 * 16 + lm][quad * 8];
            short8 bl = *(const short8*)&BsmL[j4 * 16 + lm][quad * 8];
            acc[j4] = __builtin_amdgcn_mfma_f32_16x16x32_bf16(al, bh, acc[j4], 0, 0, 0);
            acc[j4] = __builtin_amdgcn_mfma_f32_16x16x32_bf16(ah, bl, acc[j4], 0, 0, 0);
            acc[j4] = __builtin_amdgcn_mfma_f32_16x16x32_bf16(ah, bh, acc[j4], 0, 0, 0);
        }
        __syncthreads();
    }

    #pragma unroll
    for (int j4 = 0; j4 < 4; j4++) {
        const int n = n0 + j4 * 16 + lm;
        const float bn = bias[n];
        #pragma unroll
        for (int rg = 0; rg < 4; rg++) {
            const size_t m = m0 + wv * 16 + quad * 4 + rg;
            out[m * kC + n] = acc[j4][rg] + bn;
        }
    }
}

// ---------------------------------------------------------------------------
// 2) MFMA GEMM, bf16 inputs: out = epi(A @ W^T + bias [+resid]).
//    A (MxK) bf16 row-major, W (NxK) bf16 row-major; fp32 accumulate.
// ---------------------------------------------------------------------------
__global__ __launch_bounds__(256) void mfma_gemm_bf(
    const short* __restrict__ A, const short* __restrict__ W,
    const float* __restrict__ bias, const float* __restrict__ resid,
    float* __restrict__ out, short* __restrict__ outbf,
    int M, int Nout, int K, int epi)
{
    __shared__ __align__(16) short Asm[64][40];   // 32 data + 8 pad (16B rows)
    __shared__ __align__(16) short Bsm[64][40];

    const int tid = threadIdx.x;
    const int n0 = blockIdx.x * 64;
    const int m0 = blockIdx.y * 64;
    const int lane = tid & 63, wv = tid >> 6;
    const int lm = lane & 15, quad = lane >> 4;
    const int r = tid >> 2, q = tid & 3;          // staging: row r, k-quarter q

    float4v acc[4] = {};

    for (int k0 = 0; k0 < K; k0 += 32) {
        *(short8*)&Asm[r][q * 8] = *(const short8*)&A[(size_t)(m0 + r) * K + k0 + q * 8];
        *(short8*)&Bsm[r][q * 8] = *(const short8*)&W[(size_t)(n0 + r) * K + k0 + q * 8];
        __syncthreads();

        short8 af = *(const short8*)&Asm[wv * 16 + lm][quad * 8];
        #pragma unroll
        for (int j4 = 0; j4 < 4; j4++) {
            short8 bf = *(const short8*)&Bsm[j4 * 16 + lm][quad * 8];
            acc[j4] = __builtin_amdgcn_mfma_f32_16x16x32_bf16(af, bf, acc[j4], 0, 0, 0);
        }
        __syncthreads();
    }

    #pragma unroll
    for (int j4 = 0; j4 < 4; j4++) {
        const int n = n0 + j4 * 16 + lm;
        const float bn = bias[n];
        #pragma unroll
        for (int rg = 0; rg < 4; rg++) {
            const int m = m0 + wv * 16 + quad * 4 + rg;
            float v = acc[j4][rg] + bn;
            if (resid) v += resid[(size_t)m * Nout + n];
            if (epi == 1) v = gelu_erf(v);
            if (out)   out[(size_t)m * Nout + n] = v;
            if (outbf) outbf[(size_t)m * Nout + n] = f2b(v);
        }
    }
}

// ---------------------------------------------------------------------------
// 3) LayerNorm over C=256, one block per row, in place; also emits bf16 copy.
// ---------------------------------------------------------------------------
__global__ __launch_bounds__(256) void ln_kernel(
    float* __restrict__ x, short* __restrict__ xbf,
    const float* __restrict__ g, const float* __restrict__ bb)
{
    const size_t row = blockIdx.x;
    const int t = threadIdx.x;
    float v = x[row * kC + t];

    __shared__ float red4[4];
    float s = v;
    #pragma unroll
    for (int off = 32; off; off >>= 1) s += __shfl_xor(s, off, 64);
    if ((t & 63) == 0) red4[t >> 6] = s;
    __syncthreads();
    float mean = (red4[0] + red4[1] + red4[2] + red4[3]) * (1.0f / kC);

    float d = v - mean;
    float s2 = d * d;
    #pragma unroll
    for (int off = 32; off; off >>= 1) s2 += __shfl_xor(s2, off, 64);
    __syncthreads();
    if ((t & 63) == 0) red4[t >> 6] = s2;
    __syncthreads();
    float var = (red4[0] + red4[1] + red4[2] + red4[3]) * (1.0f / kC);

    float r = 1.0f / sqrtf(var + 1e-5f);
    float o = d * r * g[t] + bb[t];
    x[row * kC + t] = o;
    xbf[row * kC + t] = f2b(o);
}

// ---------------------------------------------------------------------------
// 4) wave-per-query KNN, tournament-tree selection (bit-identical ordering).
// ---------------------------------------------------------------------------
#define KNN_RESCAN(CH, BM, BI)                                        \
    do {                                                              \
        float nb_ = 1e30f; int ni_ = kN;                              \
        _Pragma("unroll")                                             \
        for (int c8_ = 0; c8_ < 8; c8_++) {                           \
            int c_ = (CH) * 8 + c8_;                                  \
            float dd_ = (mask & (1u << c_)) ? 1e30f : cd[c_];         \
            if (dd_ < nb_) { nb_ = dd_; ni_ = c_ * 64 + lane; }       \
        }                                                             \
        BM = nb_; BI = ni_;                                           \
    } while (0)

__global__ __launch_bounds__(512) void knn_kernel(
    const float* __restrict__ pos,
    const float* __restrict__ Wr1, const float* __restrict__ br1,
    const float* __restrict__ Wr2, const float* __restrict__ br2,
    int* __restrict__ idx_out, float* __restrict__ bias_out)
{
    __shared__ float px[kN], py[kN], pz[kN];
    __shared__ int selS[8][kKNN];

    const int b = blockIdx.y;
    const int t = threadIdx.x;
    const int lane = t & 63, wv = t >> 6;
    const int n = blockIdx.x * 8 + wv;

    const float* pb = pos + (size_t)b * 3 * kN;
    for (int m = t; m < kN; m += 512) {
        px[m] = pb[m]; py[m] = pb[kN + m]; pz[m] = pb[2 * kN + m];
    }
    __syncthreads();

    const float qx = px[n], qy = py[n], qz = pz[n];
    const float qsq = __fadd_rn(__fadd_rn(__fmul_rn(qx, qx), __fmul_rn(qy, qy)),
                                __fmul_rn(qz, qz));

    float cd[32];
    float bm0 = 1e30f, bm1 = 1e30f, bm2 = 1e30f, bm3 = 1e30f;
    int bi0 = kN, bi1 = kN, bi2 = kN, bi3 = kN;
    #pragma unroll
    for (int c8 = 0; c8 < 8; c8++) {
        {
            const int c = c8, m = c * 64 + lane;
            float ax = px[m], ay = py[m], az = pz[m];
            float asq = __fadd_rn(__fadd_rn(__fmul_rn(ax, ax), __fmul_rn(ay, ay)), __fmul_rn(az, az));
            float dot = __fadd_rn(__fadd_rn(__fmul_rn(qx, ax), __fmul_rn(qy, ay)), __fmul_rn(qz, az));
            float d = __fsub_rn(__fadd_rn(qsq, asq), __fmul_rn(2.0f, dot));
            cd[c] = d;
            if (d < bm0) { bm0 = d; bi0 = m; }
        }
        {
            const int c = c8 + 8, m = c * 64 + lane;
            float ax = px[m], ay = py[m], az = pz[m];
            float asq = __fadd_rn(__fadd_rn(__fmul_rn(ax, ax), __fmul_rn(ay, ay)), __fmul_rn(az, az));
            float dot = __fadd_rn(__fadd_rn(__fmul_rn(qx, ax), __fmul_rn(qy, ay)), __fmul_rn(qz, az));
            float d = __fsub_rn(__fadd_rn(qsq, asq), __fmul_rn(2.0f, dot));
            cd[c] = d;
            if (d < bm1) { bm1 = d; bi1 = m; }
        }
        {
            const int c = c8 + 16, m = c * 64 + lane;
            float ax = px[m], ay = py[m], az = pz[m];
            float asq = __fadd_rn(__fadd_rn(__fmul_rn(ax, ax), __fmul_rn(ay, ay)), __fmul_rn(az, az));
            float dot = __fadd_rn(__fadd_rn(__fmul_rn(qx, ax), __fmul_rn(qy, ay)), __fmul_rn(qz, az));
            float d = __fsub_rn(__fadd_rn(qsq, asq), __fmul_rn(2.0f, dot));
            cd[c] = d;
            if (d < bm2) { bm2 = d; bi2 = m; }
        }
        {
            const int c = c8 + 24, m = c * 64 + lane;
            float ax = px[m], ay = py[m], az = pz[m];
            float asq = __fadd_rn(__fadd_rn(__fmul_rn(ax, ax), __fmul_rn(ay, ay)), __fmul_rn(az, az));
            float dot = __fadd_rn(__fadd_rn(__fmul_rn(qx, ax), __fmul_rn(qy, ay)), __fmul_rn(qz, az));
            float d = __fsub_rn(__fadd_rn(qsq, asq), __fmul_rn(2.0f, dot));
            cd[c] = d;
            if (d < bm3) { bm3 = d; bi3 = m; }
        }
    }

    unsigned mask = 0;
    for (int r = 0; r < kKNN; r++) {
        float best = bm0; int bid = bi0;
        if (bm1 < best) { best = bm1; bid = bi1; }
        if (bm2 < best) { best = bm2; bid = bi2; }
        if (bm3 < best) { best = bm3; bid = bi3; }

        #pragma unroll
        for (int off = 1; off < 64; off <<= 1) {
            float od = __shfl_xor(best, off, 64);
            int   oi = __shfl_xor(bid, off, 64);
            if (od < best || (od == best && oi < bid)) { best = od; bid = oi; }
        }
        if (lane == 0) selS[wv][r] = bid;
        if ((bid & 63) == lane) mask |= 1u << (bid >> 6);

        if (r < kKNN - 1) {
            const int sch = __builtin_amdgcn_readfirstlane(bid >> 9);
            switch (sch) {
                case 0:  KNN_RESCAN(0, bm0, bi0); break;
                case 1:  KNN_RESCAN(1, bm1, bi1); break;
                case 2:  KNN_RESCAN(2, bm2, bi2); break;
                default: KNN_RESCAN(3, bm3, bi3); break;
            }
        }
    }

    const int k = lane >> 2;
    const int part = lane & 3;
    const int m = selS[wv][k];
    const float rx = qx - px[m], ry = qy - py[m], rz = qz - pz[m];
    float partial = 0.0f;
    #pragma unroll
    for (int jj = 0; jj < 16; jj++) {
        int o = part * 16 + jj;
        float h = rx * Wr1[o * 3 + 0] + ry * Wr1[o * 3 + 1] +
                  rz * Wr1[o * 3 + 2] + br1[o];
        partial += gelu_erf(h) * Wr2[o];
    }
    partial += __shfl_xor(partial, 1, 64);
    partial += __shfl_xor(partial, 2, 64);
    if (part == 0) {
        size_t o = ((size_t)b * kN + n) * kKNN + k;
        idx_out[o] = m;
        bias_out[o] = partial + br2[0];
    }
}

// ---------------------------------------------------------------------------
// 5) sparse attention: block = (n, b), 4 waves = 4 heads, lane = d.
//    kv buffer is fused k|v with row stride 512 (k at +0, v at +256).
// ---------------------------------------------------------------------------
__global__ __launch_bounds__(256) void attn_kernel(
    const float* __restrict__ q, const float* __restrict__ kv,
    const int* __restrict__ idx, const float* __restrict__ bias,
    short* __restrict__ obf)
{
    const int n = blockIdx.x;
    const int b = blockIdx.y;
    const int t = threadIdx.x;
    const int h = t >> 6;
    const int d = t & 63;

    const size_t row = (size_t)b * kN + n;
    const float qv = q[row * kC + h * kDH + d];

    __shared__ int   sidx[kKNN];
    __shared__ float sb[kKNN];
    if (t < kKNN) { sidx[t] = idx[row * kKNN + t]; sb[t] = bias[row * kKNN + t]; }
    __syncthreads();

    float sc[kKNN];
    #pragma unroll
    for (int j = 0; j < kKNN; j++) {
        size_t kr = (size_t)b * kN + sidx[j];
        float p = qv * kv[kr * 512 + h * kDH + d];
        #pragma unroll
        for (int off = 32; off; off >>= 1) p += __shfl_xor(p, off, 64);
        sc[j] = p * 0.125f + sb[j];
    }
    float mx = sc[0];
    #pragma unroll
    for (int j = 1; j < kKNN; j++) mx = fmaxf(mx, sc[j]);
    float den = 0.0f;
    #pragma unroll
    for (int j = 0; j < kKNN; j++) { sc[j] = expf(sc[j] - mx); den += sc[j]; }
    const float inv = 1.0f / den;
    float o = 0.0f;
    #pragma unroll
    for (int j = 0; j < kKNN; j++) {
        size_t kr = (size_t)b * kN + sidx[j];
        o += sc[j] * inv * kv[kr * 512 + kC + h * kDH + d];
    }
    obf[row * kC + h * kDH + d] = f2b(o);
}

// ---------------------------------------------------------------------------
// 6) LDS-tiled transpose (b,n,c) f32 -> (b,c,n) f32 out.
// ---------------------------------------------------------------------------
__global__ __launch_bounds__(256) void transpose_f32(
    const float* __restrict__ z, float* __restrict__ out)
{
    __shared__ float tile[32][33];
    const int b = blockIdx.z;
    const int n0 = blockIdx.x * 32;
    const int c0 = blockIdx.y * 32;
    const int tx = threadIdx.x;   // 32
    const int ty = threadIdx.y;   // 8
    #pragma unroll
    for (int i = 0; i < 32; i += 8)
        tile[ty + i][tx] = z[(size_t)b * kN * kC + (size_t)(n0 + ty + i) * kC + (c0 + tx)];
    __syncthreads();
    #pragma unroll
    for (int i = 0; i < 32; i += 8)
        out[(size_t)b * kC * kN + (size_t)(c0 + ty + i) * kN + (n0 + tx)] =
            tile[tx][ty + i];
}

// ---------------------------------------------------------------------------
extern "C" void kernel_launch(void* const* d_in, const int* in_sizes, int n_in,
                              void* d_out, int out_size, void* d_ws, size_t ws_size,
                              hipStream_t stream)
{
    const float* src1 = (const float*)d_in[0];
    const float* src2 = (const float*)d_in[1];
    const float* pos  = (const float*)d_in[2];
    const float* Wp   = (const float*)d_in[3];
    const float* bp   = (const float*)d_in[4];
    const float* Wr1  = (const float*)d_in[5];
    const float* br1  = (const float*)d_in[6];
    const float* Wr2  = (const float*)d_in[7];
    const float* br2  = (const float*)d_in[8];
    const float* Wqkv = (const float*)d_in[9];
    const float* bqkv = (const float*)d_in[10];
    const float* Wo   = (const float*)d_in[11];
    const float* bo   = (const float*)d_in[12];
    const float* g13  = (const float*)d_in[13];
    const float* b13  = (const float*)d_in[14];
    const float* g12  = (const float*)d_in[15];
    const float* b12  = (const float*)d_in[16];
    const float* W1   = (const float*)d_in[17];
    const float* b1   = (const float*)d_in[18];
    const float* W2   = (const float*)d_in[19];
    const float* b2   = (const float*)d_in[20];
    float* out = (float*)d_out;                      // fp32 output (b,c,n)

    const size_t S = (size_t)kB * kN * kC;  // 2,097,152 floats
    float* ws = (float*)d_ws;
    // f32 buffers
    float* x1  = ws;             // proj s1 out; LN13 in place; resid for out-proj
    float* s2  = ws + S;         // proj s2 out (contiguous after x1); zb aliases
    float* qb  = ws + 2 * S;     // q f32; yb aliases after attn
    float* kvb = ws + 3 * S;     // fused k|v f32, row stride 512 (2S); hbf aliases
    float* yb  = ws + 2 * S;     // alias qb (dead after attn)
    float* zb  = ws + S;         // alias s2 (dead after LN13)
    // bf16x2 staging for proj (dead after proj_mfma; alias qb/kvb region)
    short* srcThi = (short*)(ws + 2 * S);            // 16384x256 shorts = [2S,3S)
    short* srcTlo = (short*)(ws + 3 * S);            // 16384x256 shorts = [3S,4S)
    // bf16 buffers (as shorts)
    short* x1bf = (short*)(ws + 5 * S);              // S shorts  [5S, 5.5S)
    short* x2bf = (short*)(ws + 5 * S) + S;          // S shorts  [5.5S, 6S)
    short* ybf  = (short*)(ws + 6 * S);              // S shorts  [6S, 6.5S)
    short* obf  = (short*)(ws + 6 * S) + S;          // S shorts  [6.5S, 7S)
    short* hbf  = (short*)(ws + 3 * S);              // alias kvb: 4S shorts (M x DFF)
    // knn outputs
    int*   idxb  = (int*)(ws + 7 * S);
    float* biasb = ws + 7 * S + (size_t)kB * kN * kKNN;
    // bf16 weights (contiguous): [qkv][o][w1][w2][wp_hi][wp_lo]
    short* wbf    = (short*)(ws + 7 * S + 2 * (size_t)kB * kN * kKNN);
    short* Wqkvbf = wbf;                  // 196608 shorts
    short* Wobf   = wbf + 196608;         // 65536
    short* W1bf   = wbf + 262144;         // 262144
    short* W2bf   = wbf + 524288;         // 262144
    short* Wphi   = wbf + 786432;         // 65536
    short* Wplo   = wbf + 851968;         // 65536

    const int M = kB * kN;  // 8192

    // 0) weight conversions (independent of data path)
    cvt_weights<<<384, 256, 0, stream>>>(Wqkv, Wo, W1, W2, wbf);
    cvt_wp<<<32, 256, 0, stream>>>(Wp, Wphi, Wplo);

    // 1) input projection: transpose+split src, then bf16x3 MFMA GEMM
    transpose_cvt<<<dim3(kN / 32, kC / 32, 8), dim3(32, 8), 0, stream>>>(
        src1, src2, srcThi, srcTlo);
    proj_mfma<<<dim3(kC / 64, 2 * M / 64), 256, 0, stream>>>(
        srcThi, srcTlo, Wphi, Wplo, bp, x1);   // writes x1 then s2 (contiguous)

    // 2) LN13: x1,s2 contiguous; x1bf,x2bf contiguous -> one launch
    ln_kernel<<<2 * M, 256, 0, stream>>>(x1, x1bf, g13, b13);

    // 3) KNN + rel-pos bias
    knn_kernel<<<dim3(kN / 8, kB), 512, 0, stream>>>(pos, Wr1, br1, Wr2, br2, idxb, biasb);

    // 4) q projection; fused k|v projection (Wk,Wv contiguous rows of Wqkv)
    //    (qb/kvb overwrite srcThi/srcTlo -- dead after proj_mfma)
    mfma_gemm_bf<<<dim3(kC / 64, M / 64), 256, 0, stream>>>(
        x1bf, Wqkvbf, bqkv, nullptr, qb, nullptr, M, kC, kC, 0);
    mfma_gemm_bf<<<dim3(2 * kC / 64, M / 64), 256, 0, stream>>>(
        x2bf, Wqkvbf + (size_t)kC * kC, bqkv + kC, nullptr, kvb, nullptr, M, 2 * kC, kC, 0);

    // 5) sparse attention (bf16 out)
    attn_kernel<<<dim3(kN, kB), 256, 0, stream>>>(qb, kvb, idxb, biasb, obf);

    // 6) out-proj + residual(x1), then LN12
    mfma_gemm_bf<<<dim3(kC / 64, M / 64), 256, 0, stream>>>(
        obf, Wobf, bo, x1, yb, nullptr, M, kC, kC, 0);
    ln_kernel<<<M, 256, 0, stream>>>(yb, ybf, g12, b12);

    // 7) FFN: ffn1 writes bf16 only (sole consumer is ffn2 A); ffn2 f32+resid
    mfma_gemm_bf<<<dim3(kDFF / 64, M / 64), 256, 0, stream>>>(
        ybf, W1bf, b1, nullptr, nullptr, hbf, M, kDFF, kC, 1);
    mfma_gemm_bf<<<dim3(kC / 64, M / 64), 256, 0, stream>>>(
        hbf, W2bf, b2, yb, zb, nullptr, M, kC, kDFF, 0);

    // 8) transpose to (b,c,n), fp32
    transpose_f32<<<dim3(kN / 32, kC / 32, kB), dim3(32, 8), 0, stream>>>(zb, out);
}

// Round 7
// 304.478 us; speedup vs baseline: 1.4693x; 1.0201x over previous
//
#include <hip/hip_runtime.h>
#include <hip/hip_bf16.h>
#include <math.h>

// Problem constants
constexpr int kB = 4;
constexpr int kN = 2048;
constexpr int kC = 256;
constexpr int kDFF = 1024;
constexpr int kKNN = 16;
constexpr int kDH = 64;

typedef __attribute__((ext_vector_type(8))) short short8;
typedef __attribute__((ext_vector_type(4))) float float4v;

__device__ __forceinline__ float gelu_erf(float x) {
    return 0.5f * x * (1.0f + erff(x * 0.70710678118654752440f));
}

// fp32 -> bf16 bits, round-to-nearest-even (bit-exact with HW conversion)
__device__ __forceinline__ short f2b(float f) {
    unsigned u = __float_as_uint(f);
    u = u + 0x7FFFu + ((u >> 16) & 1u);
    return (short)(u >> 16);
}

// bf16 bits -> fp32 (exact)
__device__ __forceinline__ float b2f(short h) {
    unsigned u = ((unsigned)(unsigned short)h) << 16;
    return __uint_as_float(u);
}

// ---------------------------------------------------------------------------
// 0a) one-shot weight conversion f32 -> bf16 into contiguous workspace block:
//     [Wqkv 196608][Wo 65536][W1 262144][W2 262144]  (all counts % 8 == 0)
// ---------------------------------------------------------------------------
__global__ __launch_bounds__(256) void cvt_weights(
    const float* __restrict__ Wqkv, const float* __restrict__ Wo,
    const float* __restrict__ W1, const float* __restrict__ W2,
    short* __restrict__ dst)
{
    const int i = (blockIdx.x * 256 + threadIdx.x) * 8;
    const float* src; int off;
    if (i < 196608)      { src = Wqkv; off = i; }
    else if (i < 262144) { src = Wo;   off = i - 196608; }
    else if (i < 524288) { src = W1;   off = i - 262144; }
    else                 { src = W2;   off = i - 524288; }
    short8 v;
    #pragma unroll
    for (int j = 0; j < 8; j++) v[j] = f2b(src[off + j]);
    *(short8*)&dst[i] = v;
}

// ---------------------------------------------------------------------------
// 0b) Wp -> hi/lo bf16 split (v = hi + lo exactly to ~2^-18 rel).
// ---------------------------------------------------------------------------
__global__ __launch_bounds__(256) void cvt_wp(
    const float* __restrict__ Wp, short* __restrict__ hi, short* __restrict__ lo)
{
    const int i = (blockIdx.x * 256 + threadIdx.x) * 8;
    short8 h, l;
    #pragma unroll
    for (int j = 0; j < 8; j++) {
        float v = Wp[i + j];
        short hh = f2b(v);
        h[j] = hh;
        l[j] = f2b(v - b2f(hh));
    }
    *(short8*)&hi[i] = h;
    *(short8*)&lo[i] = l;
}

// ---------------------------------------------------------------------------
// 0c) src (b,C,N) f32 -> srcT (z,N,C) bf16 hi/lo, z = s*4+b (rows 0..16383).
// ---------------------------------------------------------------------------
__global__ __launch_bounds__(256) void transpose_cvt(
    const float* __restrict__ src1, const float* __restrict__ src2,
    short* __restrict__ hiT, short* __restrict__ loT)
{
    __shared__ float tile[32][33];
    const int z = blockIdx.z;
    const float* in = (z < 4 ? src1 : src2) + (size_t)(z & 3) * kC * kN;
    const int n0 = blockIdx.x * 32;
    const int c0 = blockIdx.y * 32;
    const int tx = threadIdx.x;   // 32
    const int ty = threadIdx.y;   // 8
    #pragma unroll
    for (int i = 0; i < 32; i += 8)
        tile[ty + i][tx] = in[(size_t)(c0 + ty + i) * kN + (n0 + tx)];
    __syncthreads();
    #pragma unroll
    for (int i = 0; i < 32; i += 8) {
        float v = tile[tx][ty + i];                 // src[c0+tx][n0+ty+i]
        short h = f2b(v);
        short l = f2b(v - b2f(h));
        size_t o = ((size_t)z * kN + (n0 + ty + i)) * kC + (c0 + tx);
        hiT[o] = h;
        loT[o] = l;
    }
}

// ---------------------------------------------------------------------------
// 1) input_proj as bf16x3 MFMA GEMM (numerically ~f32: err ~2^-17 rel).
// ---------------------------------------------------------------------------
__global__ __launch_bounds__(256) void proj_mfma(
    const short* __restrict__ Ahi, const short* __restrict__ Alo,
    const short* __restrict__ Whi, const short* __restrict__ Wlo,
    const float* __restrict__ bias, float* __restrict__ out)
{
    __shared__ __align__(16) short AsmH[64][40], AsmL[64][40];
    __shared__ __align__(16) short BsmH[64][40], BsmL[64][40];

    const int tid = threadIdx.x;
    const int n0 = blockIdx.x * 64;
    const size_t m0 = (size_t)blockIdx.y * 64;
    const int lane = tid & 63, wv = tid >> 6;
    const int lm = lane & 15, quad = lane >> 4;
    const int r = tid >> 2, q = tid & 3;

    float4v acc[4] = {};

    for (int k0 = 0; k0 < kC; k0 += 32) {
        *(short8*)&AsmH[r][q * 8] = *(const short8*)&Ahi[(m0 + r) * kC + k0 + q * 8];
        *(short8*)&AsmL[r][q * 8] = *(const short8*)&Alo[(m0 + r) * kC + k0 + q * 8];
        *(short8*)&BsmH[r][q * 8] = *(const short8*)&Whi[(size_t)(n0 + r) * kC + k0 + q * 8];
        *(short8*)&BsmL[r][q * 8] = *(const short8*)&Wlo[(size_t)(n0 + r) * kC + k0 + q * 8];
        __syncthreads();

        short8 ah = *(const short8*)&AsmH[wv * 16 + lm][quad * 8];
        short8 al = *(const short8*)&AsmL[wv * 16 + lm][quad * 8];
        #pragma unroll
        for (int j4 = 0; j4 < 4; j4++) {
            short8 bh = *(const short8*)&BsmH[j4 * 16 + lm][quad * 8];
            short8 bl = *(const short8*)&BsmL[j4 * 16 + lm][quad * 8];
            acc[j4] = __builtin_amdgcn_mfma_f32_16x16x32_bf16(al, bh, acc[j4], 0, 0, 0);
            acc[j4] = __builtin_amdgcn_mfma_f32_16x16x32_bf16(ah, bl, acc[j4], 0, 0, 0);
            acc[j4] = __builtin_amdgcn_mfma_f32_16x16x32_bf16(ah, bh, acc[j4], 0, 0, 0);
        }
        __syncthreads();
    }

    #pragma unroll
    for (int j4 = 0; j4 < 4; j4++) {
        const int n = n0 + j4 * 16 + lm;
        const float bn = bias[n];
        #pragma unroll
        for (int rg = 0; rg < 4; rg++) {
            const size_t m = m0 + wv * 16 + quad * 4 + rg;
            out[m * kC + n] = acc[j4][rg] + bn;
        }
    }
}

// ---------------------------------------------------------------------------
// 2a) MFMA GEMM, bf16 inputs: out = epi(A @ W^T + bias [+resid]).
// ---------------------------------------------------------------------------
__global__ __launch_bounds__(256) void mfma_gemm_bf(
    const short* __restrict__ A, const short* __restrict__ W,
    const float* __restrict__ bias, const float* __restrict__ resid,
    float* __restrict__ out, short* __restrict__ outbf,
    int M, int Nout, int K, int epi)
{
    __shared__ __align__(16) short Asm[64][40];   // 32 data + 8 pad (16B rows)
    __shared__ __align__(16) short Bsm[64][40];

    const int tid = threadIdx.x;
    const int n0 = blockIdx.x * 64;
    const int m0 = blockIdx.y * 64;
    const int lane = tid & 63, wv = tid >> 6;
    const int lm = lane & 15, quad = lane >> 4;
    const int r = tid >> 2, q = tid & 3;          // staging: row r, k-quarter q

    float4v acc[4] = {};

    for (int k0 = 0; k0 < K; k0 += 32) {
        *(short8*)&Asm[r][q * 8] = *(const short8*)&A[(size_t)(m0 + r) * K + k0 + q * 8];
        *(short8*)&Bsm[r][q * 8] = *(const short8*)&W[(size_t)(n0 + r) * K + k0 + q * 8];
        __syncthreads();

        short8 af = *(const short8*)&Asm[wv * 16 + lm][quad * 8];
        #pragma unroll
        for (int j4 = 0; j4 < 4; j4++) {
            short8 bf = *(const short8*)&Bsm[j4 * 16 + lm][quad * 8];
            acc[j4] = __builtin_amdgcn_mfma_f32_16x16x32_bf16(af, bf, acc[j4], 0, 0, 0);
        }
        __syncthreads();
    }

    #pragma unroll
    for (int j4 = 0; j4 < 4; j4++) {
        const int n = n0 + j4 * 16 + lm;
        const float bn = bias[n];
        #pragma unroll
        for (int rg = 0; rg < 4; rg++) {
            const int m = m0 + wv * 16 + quad * 4 + rg;
            float v = acc[j4][rg] + bn;
            if (resid) v += resid[(size_t)m * Nout + n];
            if (epi == 1) v = gelu_erf(v);
            if (out)   out[(size_t)m * Nout + n] = v;
            if (outbf) outbf[(size_t)m * Nout + n] = f2b(v);
        }
    }
}

// ---------------------------------------------------------------------------
// 2b) merged q + kv projection: one dispatch over Nglobal = 768 columns.
//     n0g <  256: A = x1bf, out = qb  (Nout 256, col n0g)
//     n0g >= 256: A = x2bf, out = kvb (Nout 512, col n0g-256)
//     W rows = Wqkv rows n0g..n0g+63; bias = bqkv[n0g + ...]. K = 256.
// ---------------------------------------------------------------------------
__global__ __launch_bounds__(256) void qkv_gemm(
    const short* __restrict__ x1bf, const short* __restrict__ x2bf,
    const short* __restrict__ Wqkvbf, const float* __restrict__ bqkv,
    float* __restrict__ qb, float* __restrict__ kvb)
{
    __shared__ __align__(16) short Asm[64][40];
    __shared__ __align__(16) short Bsm[64][40];

    const int n0g = blockIdx.x * 64;            // 0..704
    const int m0 = blockIdx.y * 64;
    const short* A; float* out; int Nout; int ncol0;
    if (n0g < 256) { A = x1bf; out = qb;  Nout = 256; ncol0 = n0g; }
    else           { A = x2bf; out = kvb; Nout = 512; ncol0 = n0g - 256; }

    const int tid = threadIdx.x;
    const int lane = tid & 63, wv = tid >> 6;
    const int lm = lane & 15, quad = lane >> 4;
    const int r = tid >> 2, q = tid & 3;

    float4v acc[4] = {};

    for (int k0 = 0; k0 < kC; k0 += 32) {
        *(short8*)&Asm[r][q * 8] = *(const short8*)&A[(size_t)(m0 + r) * kC + k0 + q * 8];
        *(short8*)&Bsm[r][q * 8] = *(const short8*)&Wqkvbf[(size_t)(n0g + r) * kC + k0 + q * 8];
        __syncthreads();

        short8 af = *(const short8*)&Asm[wv * 16 + lm][quad * 8];
        #pragma unroll
        for (int j4 = 0; j4 < 4; j4++) {
            short8 bf = *(const short8*)&Bsm[j4 * 16 + lm][quad * 8];
            acc[j4] = __builtin_amdgcn_mfma_f32_16x16x32_bf16(af, bf, acc[j4], 0, 0, 0);
        }
        __syncthreads();
    }

    #pragma unroll
    for (int j4 = 0; j4 < 4; j4++) {
        const int nc = ncol0 + j4 * 16 + lm;
        const float bn = bqkv[n0g + j4 * 16 + lm];
        #pragma unroll
        for (int rg = 0; rg < 4; rg++) {
            const int m = m0 + wv * 16 + quad * 4 + rg;
            out[(size_t)m * Nout + nc] = acc[j4][rg] + bn;
        }
    }
}

// ---------------------------------------------------------------------------
// 3) LayerNorm over C=256, one block per row, in place; also emits bf16 copy.
// ---------------------------------------------------------------------------
__global__ __launch_bounds__(256) void ln_kernel(
    float* __restrict__ x, short* __restrict__ xbf,
    const float* __restrict__ g, const float* __restrict__ bb)
{
    const size_t row = blockIdx.x;
    const int t = threadIdx.x;
    float v = x[row * kC + t];

    __shared__ float red4[4];
    float s = v;
    #pragma unroll
    for (int off = 32; off; off >>= 1) s += __shfl_xor(s, off, 64);
    if ((t & 63) == 0) red4[t >> 6] = s;
    __syncthreads();
    float mean = (red4[0] + red4[1] + red4[2] + red4[3]) * (1.0f / kC);

    float d = v - mean;
    float s2 = d * d;
    #pragma unroll
    for (int off = 32; off; off >>= 1) s2 += __shfl_xor(s2, off, 64);
    __syncthreads();
    if ((t & 63) == 0) red4[t >> 6] = s2;
    __syncthreads();
    float var = (red4[0] + red4[1] + red4[2] + red4[3]) * (1.0f / kC);

    float r = 1.0f / sqrtf(var + 1e-5f);
    float o = d * r * g[t] + bb[t];
    x[row * kC + t] = o;
    xbf[row * kC + t] = f2b(o);
}

// ---------------------------------------------------------------------------
// 4) wave-per-query KNN, tournament-tree selection (bit-identical ordering).
//    NOW 256-thread blocks (4 waves = 4 queries): the 512-thread shape sat at
//    ~12 resident waves/CU (R2/R3/R6, invariant); 256-thread blocks allow
//    6 blocks/CU by LDS = 24 waves/CU. Per-wave algorithm unchanged.
// ---------------------------------------------------------------------------
#define KNN_RESCAN(CH, BM, BI)                                        \
    do {                                                              \
        float nb_ = 1e30f; int ni_ = kN;                              \
        _Pragma("unroll")                                             \
        for (int c8_ = 0; c8_ < 8; c8_++) {                           \
            int c_ = (CH) * 8 + c8_;                                  \
            float dd_ = (mask & (1u << c_)) ? 1e30f : cd[c_];         \
            if (dd_ < nb_) { nb_ = dd_; ni_ = c_ * 64 + lane; }       \
        }                                                             \
        BM = nb_; BI = ni_;                                           \
    } while (0)

__global__ __launch_bounds__(256) void knn_kernel(
    const float* __restrict__ pos,
    const float* __restrict__ Wr1, const float* __restrict__ br1,
    const float* __restrict__ Wr2, const float* __restrict__ br2,
    int* __restrict__ idx_out, float* __restrict__ bias_out)
{
    __shared__ float px[kN], py[kN], pz[kN];
    __shared__ int selS[4][kKNN];

    const int b = blockIdx.y;
    const int t = threadIdx.x;
    const int lane = t & 63, wv = t >> 6;
    const int n = blockIdx.x * 4 + wv;

    const float* pb = pos + (size_t)b * 3 * kN;
    for (int m = t; m < kN; m += 256) {
        px[m] = pb[m]; py[m] = pb[kN + m]; pz[m] = pb[2 * kN + m];
    }
    __syncthreads();

    const float qx = px[n], qy = py[n], qz = pz[n];
    const float qsq = __fadd_rn(__fadd_rn(__fmul_rn(qx, qx), __fmul_rn(qy, qy)),
                                __fmul_rn(qz, qz));

    float cd[32];
    float bm0 = 1e30f, bm1 = 1e30f, bm2 = 1e30f, bm3 = 1e30f;
    int bi0 = kN, bi1 = kN, bi2 = kN, bi3 = kN;
    #pragma unroll
    for (int c8 = 0; c8 < 8; c8++) {
        {
            const int c = c8, m = c * 64 + lane;
            float ax = px[m], ay = py[m], az = pz[m];
            float asq = __fadd_rn(__fadd_rn(__fmul_rn(ax, ax), __fmul_rn(ay, ay)), __fmul_rn(az, az));
            float dot = __fadd_rn(__fadd_rn(__fmul_rn(qx, ax), __fmul_rn(qy, ay)), __fmul_rn(qz, az));
            float d = __fsub_rn(__fadd_rn(qsq, asq), __fmul_rn(2.0f, dot));
            cd[c] = d;
            if (d < bm0) { bm0 = d; bi0 = m; }
        }
        {
            const int c = c8 + 8, m = c * 64 + lane;
            float ax = px[m], ay = py[m], az = pz[m];
            float asq = __fadd_rn(__fadd_rn(__fmul_rn(ax, ax), __fmul_rn(ay, ay)), __fmul_rn(az, az));
            float dot = __fadd_rn(__fadd_rn(__fmul_rn(qx, ax), __fmul_rn(qy, ay)), __fmul_rn(qz, az));
            float d = __fsub_rn(__fadd_rn(qsq, asq), __fmul_rn(2.0f, dot));
            cd[c] = d;
            if (d < bm1) { bm1 = d; bi1 = m; }
        }
        {
            const int c = c8 + 16, m = c * 64 + lane;
            float ax = px[m], ay = py[m], az = pz[m];
            float asq = __fadd_rn(__fadd_rn(__fmul_rn(ax, ax), __fmul_rn(ay, ay)), __fmul_rn(az, az));
            float dot = __fadd_rn(__fadd_rn(__fmul_rn(qx, ax), __fmul_rn(qy, ay)), __fmul_rn(qz, az));
            float d = __fsub_rn(__fadd_rn(qsq, asq), __fmul_rn(2.0f, dot));
            cd[c] = d;
            if (d < bm2) { bm2 = d; bi2 = m; }
        }
        {
            const int c = c8 + 24, m = c * 64 + lane;
            float ax = px[m], ay = py[m], az = pz[m];
            float asq = __fadd_rn(__fadd_rn(__fmul_rn(ax, ax), __fmul_rn(ay, ay)), __fmul_rn(az, az));
            float dot = __fadd_rn(__fadd_rn(__fmul_rn(qx, ax), __fmul_rn(qy, ay)), __fmul_rn(qz, az));
            float d = __fsub_rn(__fadd_rn(qsq, asq), __fmul_rn(2.0f, dot));
            cd[c] = d;
            if (d < bm3) { bm3 = d; bi3 = m; }
        }
    }

    unsigned mask = 0;
    for (int r = 0; r < kKNN; r++) {
        float best = bm0; int bid = bi0;
        if (bm1 < best) { best = bm1; bid = bi1; }
        if (bm2 < best) { best = bm2; bid = bi2; }
        if (bm3 < best) { best = bm3; bid = bi3; }

        #pragma unroll
        for (int off = 1; off < 64; off <<= 1) {
            float od = __shfl_xor(best, off, 64);
            int   oi = __shfl_xor(bid, off, 64);
            if (od < best || (od == best && oi < bid)) { best = od; bid = oi; }
        }
        if (lane == 0) selS[wv][r] = bid;
        if ((bid & 63) == lane) mask |= 1u << (bid >> 6);

        if (r < kKNN - 1) {
            const int sch = __builtin_amdgcn_readfirstlane(bid >> 9);
            switch (sch) {
                case 0:  KNN_RESCAN(0, bm0, bi0); break;
                case 1:  KNN_RESCAN(1, bm1, bi1); break;
                case 2:  KNN_RESCAN(2, bm2, bi2); break;
                default: KNN_RESCAN(3, bm3, bi3); break;
            }
        }
    }

    const int k = lane >> 2;
    const int part = lane & 3;
    const int m = selS[wv][k];
    const float rx = qx - px[m], ry = qy - py[m], rz = qz - pz[m];
    float partial = 0.0f;
    #pragma unroll
    for (int jj = 0; jj < 16; jj++) {
        int o = part * 16 + jj;
        float h = rx * Wr1[o * 3 + 0] + ry * Wr1[o * 3 + 1] +
                  rz * Wr1[o * 3 + 2] + br1[o];
        partial += gelu_erf(h) * Wr2[o];
    }
    partial += __shfl_xor(partial, 1, 64);
    partial += __shfl_xor(partial, 2, 64);
    if (part == 0) {
        size_t o = ((size_t)b * kN + n) * kKNN + k;
        idx_out[o] = m;
        bias_out[o] = partial + br2[0];
    }
}

// ---------------------------------------------------------------------------
// 5) sparse attention: block = (n, b), 4 waves = 4 heads, lane = d.
//    kv buffer is fused k|v with row stride 512 (k at +0, v at +256).
// ---------------------------------------------------------------------------
__global__ __launch_bounds__(256) void attn_kernel(
    const float* __restrict__ q, const float* __restrict__ kv,
    const int* __restrict__ idx, const float* __restrict__ bias,
    short* __restrict__ obf)
{
    const int n = blockIdx.x;
    const int b = blockIdx.y;
    const int t = threadIdx.x;
    const int h = t >> 6;
    const int d = t & 63;

    const size_t row = (size_t)b * kN + n;
    const float qv = q[row * kC + h * kDH + d];

    __shared__ int   sidx[kKNN];
    __shared__ float sb[kKNN];
    if (t < kKNN) { sidx[t] = idx[row * kKNN + t]; sb[t] = bias[row * kKNN + t]; }
    __syncthreads();

    float sc[kKNN];
    #pragma unroll
    for (int j = 0; j < kKNN; j++) {
        size_t kr = (size_t)b * kN + sidx[j];
        float p = qv * kv[kr * 512 + h * kDH + d];
        #pragma unroll
        for (int off = 32; off; off >>= 1) p += __shfl_xor(p, off, 64);
        sc[j] = p * 0.125f + sb[j];
    }
    float mx = sc[0];
    #pragma unroll
    for (int j = 1; j < kKNN; j++) mx = fmaxf(mx, sc[j]);
    float den = 0.0f;
    #pragma unroll
    for (int j = 0; j < kKNN; j++) { sc[j] = expf(sc[j] - mx); den += sc[j]; }
    const float inv = 1.0f / den;
    float o = 0.0f;
    #pragma unroll
    for (int j = 0; j < kKNN; j++) {
        size_t kr = (size_t)b * kN + sidx[j];
        o += sc[j] * inv * kv[kr * 512 + kC + h * kDH + d];
    }
    obf[row * kC + h * kDH + d] = f2b(o);
}

// ---------------------------------------------------------------------------
// 6) LDS-tiled transpose (b,n,c) f32 -> (b,c,n) f32 out.
// ---------------------------------------------------------------------------
__global__ __launch_bounds__(256) void transpose_f32(
    const float* __restrict__ z, float* __restrict__ out)
{
    __shared__ float tile[32][33];
    const int b = blockIdx.z;
    const int n0 = blockIdx.x * 32;
    const int c0 = blockIdx.y * 32;
    const int tx = threadIdx.x;   // 32
    const int ty = threadIdx.y;   // 8
    #pragma unroll
    for (int i = 0; i < 32; i += 8)
        tile[ty + i][tx] = z[(size_t)b * kN * kC + (size_t)(n0 + ty + i) * kC + (c0 + tx)];
    __syncthreads();
    #pragma unroll
    for (int i = 0; i < 32; i += 8)
        out[(size_t)b * kC * kN + (size_t)(c0 + ty + i) * kN + (n0 + tx)] =
            tile[tx][ty + i];
}

// ---------------------------------------------------------------------------
extern "C" void kernel_launch(void* const* d_in, const int* in_sizes, int n_in,
                              void* d_out, int out_size, void* d_ws, size_t ws_size,
                              hipStream_t stream)
{
    const float* src1 = (const float*)d_in[0];
    const float* src2 = (const float*)d_in[1];
    const float* pos  = (const float*)d_in[2];
    const float* Wp   = (const float*)d_in[3];
    const float* bp   = (const float*)d_in[4];
    const float* Wr1  = (const float*)d_in[5];
    const float* br1  = (const float*)d_in[6];
    const float* Wr2  = (const float*)d_in[7];
    const float* br2  = (const float*)d_in[8];
    const float* Wqkv = (const float*)d_in[9];
    const float* bqkv = (const float*)d_in[10];
    const float* Wo   = (const float*)d_in[11];
    const float* bo   = (const float*)d_in[12];
    const float* g13  = (const float*)d_in[13];
    const float* b13  = (const float*)d_in[14];
    const float* g12  = (const float*)d_in[15];
    const float* b12  = (const float*)d_in[16];
    const float* W1   = (const float*)d_in[17];
    const float* b1   = (const float*)d_in[18];
    const float* W2   = (const float*)d_in[19];
    const float* b2   = (const float*)d_in[20];
    float* out = (float*)d_out;                      // fp32 output (b,c,n)

    const size_t S = (size_t)kB * kN * kC;  // 2,097,152 floats
    float* ws = (float*)d_ws;
    // f32 buffers
    float* x1  = ws;             // proj s1 out; LN13 in place; resid for out-proj
    float* s2  = ws + S;         // proj s2 out (contiguous after x1); zb aliases
    float* qb  = ws + 2 * S;     // q f32; yb aliases after attn
    float* kvb = ws + 3 * S;     // fused k|v f32, row stride 512 (2S); hbf aliases
    float* yb  = ws + 2 * S;     // alias qb (dead after attn)
    float* zb  = ws + S;         // alias s2 (dead after LN13)
    // bf16x2 staging for proj (dead after proj_mfma; alias qb/kvb region)
    short* srcThi = (short*)(ws + 2 * S);            // 16384x256 shorts = [2S,3S)
    short* srcTlo = (short*)(ws + 3 * S);            // 16384x256 shorts = [3S,4S)
    // bf16 buffers (as shorts)
    short* x1bf = (short*)(ws + 5 * S);              // S shorts  [5S, 5.5S)
    short* x2bf = (short*)(ws + 5 * S) + S;          // S shorts  [5.5S, 6S)
    short* ybf  = (short*)(ws + 6 * S);              // S shorts  [6S, 6.5S)
    short* obf  = (short*)(ws + 6 * S) + S;          // S shorts  [6.5S, 7S)
    short* hbf  = (short*)(ws + 3 * S);              // alias kvb: 4S shorts (M x DFF)
    // knn outputs
    int*   idxb  = (int*)(ws + 7 * S);
    float* biasb = ws + 7 * S + (size_t)kB * kN * kKNN;
    // bf16 weights (contiguous): [qkv][o][w1][w2][wp_hi][wp_lo]
    short* wbf    = (short*)(ws + 7 * S + 2 * (size_t)kB * kN * kKNN);
    short* Wqkvbf = wbf;                  // 196608 shorts
    short* Wobf   = wbf + 196608;         // 65536
    short* W1bf   = wbf + 262144;         // 262144
    short* W2bf   = wbf + 524288;         // 262144
    short* Wphi   = wbf + 786432;         // 65536
    short* Wplo   = wbf + 851968;         // 65536

    const int M = kB * kN;  // 8192

    // 0) weight conversions (independent of data path)
    cvt_weights<<<384, 256, 0, stream>>>(Wqkv, Wo, W1, W2, wbf);
    cvt_wp<<<32, 256, 0, stream>>>(Wp, Wphi, Wplo);

    // 1) input projection: transpose+split src, then bf16x3 MFMA GEMM
    transpose_cvt<<<dim3(kN / 32, kC / 32, 8), dim3(32, 8), 0, stream>>>(
        src1, src2, srcThi, srcTlo);
    proj_mfma<<<dim3(kC / 64, 2 * M / 64), 256, 0, stream>>>(
        srcThi, srcTlo, Wphi, Wplo, bp, x1);   // writes x1 then s2 (contiguous)

    // 2) LN13: x1,s2 contiguous; x1bf,x2bf contiguous -> one launch
    ln_kernel<<<2 * M, 256, 0, stream>>>(x1, x1bf, g13, b13);

    // 3) KNN + rel-pos bias (256-thread blocks, 4 queries each)
    knn_kernel<<<dim3(kN / 4, kB), 256, 0, stream>>>(pos, Wr1, br1, Wr2, br2, idxb, biasb);

    // 4) merged q + kv projection (one dispatch, 1536 blocks)
    qkv_gemm<<<dim3(12, M / 64), 256, 0, stream>>>(x1bf, x2bf, Wqkvbf, bqkv, qb, kvb);

    // 5) sparse attention (bf16 out)
    attn_kernel<<<dim3(kN, kB), 256, 0, stream>>>(qb, kvb, idxb, biasb, obf);

    // 6) out-proj + residual(x1), then LN12
    mfma_gemm_bf<<<dim3(kC / 64, M / 64), 256, 0, stream>>>(
        obf, Wobf, bo, x1, yb, nullptr, M, kC, kC, 0);
    ln_kernel<<<M, 256, 0, stream>>>(yb, ybf, g12, b12);

    // 7) FFN: ffn1 writes bf16 only (sole consumer is ffn2 A); ffn2 f32+resid
    mfma_gemm_bf<<<dim3(kDFF / 64, M / 64), 256, 0, stream>>>(
        ybf, W1bf, b1, nullptr, nullptr, hbf, M, kDFF, kC, 1);
    mfma_gemm_bf<<<dim3(kC / 64, M / 64), 256, 0, stream>>>(
        hbf, W2bf, b2, yb, zb, nullptr, M, kC, kDFF, 0);

    // 8) transpose to (b,c,n), fp32
    transpose_f32<<<dim3(kN / 32, kC / 32, kB), dim3(32, 8), 0, stream>>>(zb, out);
}